// Round 1
// baseline (1513.155 us; speedup 1.0000x reference)
//
#include <hip/hip_runtime.h>
#include <math.h>

#define NV 20000
#define NE 320000

// ---------------- proj: h = gelu(LN(x@Wp + bp; gp, bep)) ----------------
__global__ __launch_bounds__(256) void proj_kernel(
    const float* __restrict__ x, const float* __restrict__ Wp,
    const float* __restrict__ bp, const float* __restrict__ gp,
    const float* __restrict__ bep, float* __restrict__ h, int N)
{
  int wid = threadIdx.x >> 6, lane = threadIdx.x & 63;
  int row = blockIdx.x * 4 + wid;
  if (row >= N) return;
  float xv = x[(size_t)row * 64 + lane];
  float acc = bp[lane];
#pragma unroll
  for (int k = 0; k < 64; ++k) {
    float a = __shfl(xv, k, 64);
    acc = fmaf(a, Wp[k * 64 + lane], acc);
  }
  float s1 = acc, s2 = acc * acc;
#pragma unroll
  for (int o = 32; o; o >>= 1) { s1 += __shfl_xor(s1, o, 64); s2 += __shfl_xor(s2, o, 64); }
  float mean = s1 * (1.0f / 64.0f);
  float var  = s2 * (1.0f / 64.0f) - mean * mean;
  float y = (acc - mean) * rsqrtf(var + 1e-5f) * gp[lane] + bep[lane];
  float gel = 0.5f * y * (1.0f + erff(y * 0.70710678118654752f));
  h[(size_t)row * 64 + lane] = gel;
}

// ---------------- generic f32 GEMM: C[N,M] = A[N,K]@W[K,M] + bias ----------------
// 64x64 tile, 1 wave/block, 8x8 microtile, k-tile 16. K%16==0, M%64==0.
__global__ __launch_bounds__(64) void gemm64_kernel(
    const float* __restrict__ A, const float* __restrict__ W,
    const float* __restrict__ bias, float* __restrict__ C,
    int N, int K, int M)
{
  __shared__ float As[16][72];  // [k][row]
  __shared__ float Ws[16][72];  // [k][col]
  int t = threadIdx.x;
  int row0 = blockIdx.y * 64;
  int col0 = blockIdx.x * 64;
  int ti = t & 7, tj = t >> 3;
  float acc[8][8];
#pragma unroll
  for (int i = 0; i < 8; ++i)
#pragma unroll
    for (int j = 0; j < 8; ++j) acc[i][j] = 0.0f;

  int arow = row0 + t;
  bool arow_ok = arow < N;

  for (int k0 = 0; k0 < K; k0 += 16) {
    {  // A tile: thread t loads 16 k-values of row t, stores transposed
      const float4* ap = (const float4*)(A + (size_t)arow * K + k0);
#pragma unroll
      for (int q = 0; q < 4; ++q) {
        float4 v = arow_ok ? ap[q] : make_float4(0.f, 0.f, 0.f, 0.f);
        As[q * 4 + 0][t] = v.x; As[q * 4 + 1][t] = v.y;
        As[q * 4 + 2][t] = v.z; As[q * 4 + 3][t] = v.w;
      }
    }
    {  // W tile: kk = t>>2 row, 16 floats each
      int kk = t >> 2, jg = t & 3;
      const float4* wp = (const float4*)(W + (size_t)(k0 + kk) * M + col0);
#pragma unroll
      for (int q = 0; q < 4; ++q) {
        float4 v = wp[jg * 4 + q];
        *((float4*)&Ws[kk][jg * 16 + q * 4]) = v;
      }
    }
    __syncthreads();
#pragma unroll
    for (int kk = 0; kk < 16; ++kk) {
      float a[8], b[8];
      *(float4*)&a[0] = *(const float4*)&As[kk][ti * 8];
      *(float4*)&a[4] = *(const float4*)&As[kk][ti * 8 + 4];
      *(float4*)&b[0] = *(const float4*)&Ws[kk][tj * 8];
      *(float4*)&b[4] = *(const float4*)&Ws[kk][tj * 8 + 4];
#pragma unroll
      for (int i = 0; i < 8; ++i)
#pragma unroll
        for (int j = 0; j < 8; ++j) acc[i][j] = fmaf(a[i], b[j], acc[i][j]);
    }
    __syncthreads();
  }

  float bb[8];
#pragma unroll
  for (int j = 0; j < 8; ++j) bb[j] = bias[col0 + tj * 8 + j];
#pragma unroll
  for (int i = 0; i < 8; ++i) {
    int r = row0 + ti * 8 + i;
    if (r < N) {
      float* cp = C + (size_t)r * M + col0 + tj * 8;
      float4 o0 = make_float4(acc[i][0] + bb[0], acc[i][1] + bb[1],
                              acc[i][2] + bb[2], acc[i][3] + bb[3]);
      float4 o1 = make_float4(acc[i][4] + bb[4], acc[i][5] + bb[5],
                              acc[i][6] + bb[6], acc[i][7] + bb[7]);
      *((float4*)cp) = o0;
      *((float4*)(cp + 4)) = o1;
    }
  }
}

// ---------------- edge-attr column sums (for self-loop mean) ----------------
__global__ __launch_bounds__(256) void colsum_kernel(
    const float* __restrict__ ea, float* __restrict__ easum, int E)
{
  int t = threadIdx.x;
  int col = t & 15;
  int r = blockIdx.x * 16 + (t >> 4);
  int rstride = gridDim.x * 16;
  float s = 0.0f;
  for (; r < E; r += rstride) s += ea[(size_t)r * 16 + col];
  __shared__ float red[256];
  red[t] = s;
  __syncthreads();
  if (t < 16) {
    float tot = 0.0f;
    for (int j = t; j < 256; j += 16) tot += red[j];
    atomicAdd(&easum[t], tot);
  }
}

// ---------------- CSR build ----------------
__global__ __launch_bounds__(256) void hist_kernel(
    const int* __restrict__ ei, int* __restrict__ counts, int E, int total)
{
  int i = blockIdx.x * 256 + threadIdx.x;
  if (i >= total) return;
  int dst = (i < E) ? ei[E + i] : (i - E);
  atomicAdd(&counts[dst], 1);
}

__global__ __launch_bounds__(1024) void scan_kernel(
    int* __restrict__ counts /* [N+1] in/out -> exclusive offsets */,
    int* __restrict__ cursor, int N)
{
  __shared__ int wsum[16];
  __shared__ int running_s;
  int t = threadIdx.x;
  int lane = t & 63, wid = t >> 6;
  if (t == 0) running_s = 0;
  __syncthreads();
  for (int base = 0; base < N; base += 1024) {
    int i = base + t;
    int v = (i < N) ? counts[i] : 0;
    int x = v;
#pragma unroll
    for (int o = 1; o < 64; o <<= 1) {
      int y = __shfl_up(x, o, 64);
      if (lane >= o) x += y;
    }
    if (lane == 63) wsum[wid] = x;
    __syncthreads();
    int prefix = 0;
    for (int wj = 0; wj < wid; ++wj) prefix += wsum[wj];
    int run = running_s;
    int excl = run + prefix + x - v;
    if (i < N) { counts[i] = excl; cursor[i] = excl; }
    __syncthreads();
    if (t == 1023) running_s = run + prefix + x;
    __syncthreads();
  }
  if (t == 0) counts[N] = running_s;
}

__global__ __launch_bounds__(256) void scatter_kernel(
    const int* __restrict__ ei, int* __restrict__ cursor,
    int* __restrict__ csr, int E, int total)
{
  int i = blockIdx.x * 256 + threadIdx.x;
  if (i >= total) return;
  int dst = (i < E) ? ei[E + i] : (i - E);
  int pos = atomicAdd(&cursor[dst], 1);
  csr[pos] = i;
}

// ---------------- GATv2 aggregate + epilogue (softmax w/o max-shift, LN, gelu, +res) ----------------
// One block per dst node; H waves, wave h = head h, lane = channel.
template <int H>
__global__ __launch_bounds__(H * 64) void aggregate_kernel(
    const int* __restrict__ ei, const float* __restrict__ ea,
    const float* __restrict__ easum,
    const float* __restrict__ xl, const float* __restrict__ xr,
    const float* __restrict__ We, const float* __restrict__ att,
    const float* __restrict__ bc, const float* __restrict__ g,
    const float* __restrict__ be,
    const float* res,            // may alias hout (same element per thread)
    const int* __restrict__ offs, const int* __restrict__ csr,
    float* hout, int E, int N)
{
  const int HC = H * 64;
  int n = blockIdx.x;
  int t = threadIdx.x;
  int lane = t & 63;
  float xr_t = xr[(size_t)n * HC + t];
  float att_t = att[t];
  float Wc[16];
#pragma unroll
  for (int k = 0; k < 16; ++k) Wc[k] = We[k * HC + t];
  const float invE = 1.0f / (float)E;
  float acc = 0.0f, denom = 0.0f;
  int beg = offs[n], end = offs[n + 1];
  for (int idx = beg; idx < end; ++idx) {
    int e = csr[idx];
    int src;
    float eav[16];
    if (e < E) {
      src = ei[e];
      const float4* p = (const float4*)(ea + (size_t)e * 16);
      float4 q0 = p[0], q1 = p[1], q2 = p[2], q3 = p[3];
      eav[0] = q0.x; eav[1] = q0.y; eav[2]  = q0.z; eav[3]  = q0.w;
      eav[4] = q1.x; eav[5] = q1.y; eav[6]  = q1.z; eav[7]  = q1.w;
      eav[8] = q2.x; eav[9] = q2.y; eav[10] = q2.z; eav[11] = q2.w;
      eav[12] = q3.x; eav[13] = q3.y; eav[14] = q3.z; eav[15] = q3.w;
    } else {
      src = e - E;  // self loop: src == n
#pragma unroll
      for (int k = 0; k < 16; ++k) eav[k] = easum[k] * invE;
    }
    float ee = 0.0f;
#pragma unroll
    for (int k = 0; k < 16; ++k) ee = fmaf(eav[k], Wc[k], ee);
    float xls = xl[(size_t)src * HC + t];
    float v = xls + xr_t + ee;
    v = v > 0.0f ? v : 0.2f * v;  // leaky_relu(0.2)
    float s = v * att_t;
#pragma unroll
    for (int o = 32; o; o >>= 1) s += __shfl_xor(s, o, 64);
    float w = expf(s);
    acc = fmaf(w, xls, acc);
    denom += w;
  }
  float out = acc / (denom + 1e-16f) + bc[t];

  // LayerNorm across HC channels
  float s1 = out, s2 = out * out;
#pragma unroll
  for (int o = 32; o; o >>= 1) { s1 += __shfl_xor(s1, o, 64); s2 += __shfl_xor(s2, o, 64); }
  if (H > 1) {
    __shared__ float r1[4], r2[4];
    int wid = t >> 6;
    if (lane == 0) { r1[wid] = s1; r2[wid] = s2; }
    __syncthreads();
    s1 = 0.0f; s2 = 0.0f;
#pragma unroll
    for (int j = 0; j < H; ++j) { s1 += r1[j]; s2 += r2[j]; }
  }
  float mean = s1 / (float)HC;
  float var  = s2 / (float)HC - mean * mean;
  float y = (out - mean) * rsqrtf(var + 1e-5f) * g[t] + be[t];
  float gel = 0.5f * y * (1.0f + erff(y * 0.70710678118654752f));
  float r = res[(size_t)n * HC + t];  // read BEFORE write: hout may alias res
  hout[(size_t)n * HC + t] = gel + r;
}

// ---------------- host launch ----------------
extern "C" void kernel_launch(void* const* d_in, const int* in_sizes, int n_in,
                              void* d_out, int out_size, void* d_ws, size_t ws_size,
                              hipStream_t stream)
{
  const float* x = (const float*)d_in[0];
  const int*   ei[3] = {(const int*)d_in[1], (const int*)d_in[3], (const int*)d_in[5]};
  const float* ea[3] = {(const float*)d_in[2], (const float*)d_in[4], (const float*)d_in[6]};
  const float* Wp  = (const float*)d_in[7];
  const float* bp  = (const float*)d_in[8];
  const float* gp  = (const float*)d_in[9];
  const float* bep = (const float*)d_in[10];
  auto in = [&](int i) { return (const float*)d_in[i]; };
  // per-layer base 11 + 11*i: Wl, bl, Wr, br, We, att, bc, g, be, Wsk, bsk

  // workspace layout
  const size_t NB = (size_t)NV * 256 * sizeof(float);  // 20.48 MB
  char* w = (char*)d_ws;
  float* B0 = (float*)(w);
  float* B1 = (float*)(w + NB);
  float* B2 = (float*)(w + 2 * NB);
  float* B3 = (float*)(w + 3 * NB);
  char*  ib = w + 4 * NB;
  float* easum  = (float*)ib;                    // 16 floats (64 B)
  int*   counts = (int*)(ib + 64);               // N+1 ints (padded to 80064 B)
  int*   cursor = (int*)(ib + 64 + 80064);       // N ints
  int*   csr    = (int*)(ib + 64 + 80064 + 80000);  // E+N ints

  auto gemm = [&](const float* A, const float* W, const float* b, float* C,
                  int N, int K, int M) {
    dim3 gsz(M / 64, (N + 63) / 64);
    gemm64_kernel<<<gsz, 64, 0, stream>>>(A, W, b, C, N, K, M);
  };
  auto build_csr = [&](const int* ei_l, const float* ea_l) {
    hipMemsetAsync(easum, 0, 64 + (size_t)(NV + 1) * 4, stream);
    colsum_kernel<<<64, 256, 0, stream>>>(ea_l, easum, NE);
    hist_kernel<<<(NE + NV + 255) / 256, 256, 0, stream>>>(ei_l, counts, NE, NE + NV);
    scan_kernel<<<1, 1024, 0, stream>>>(counts, cursor, NV);
    scatter_kernel<<<(NE + NV + 255) / 256, 256, 0, stream>>>(ei_l, cursor, csr, NE, NE + NV);
  };

  // input projection -> B0 [N,64]
  proj_kernel<<<(NV + 3) / 4, 256, 0, stream>>>(x, Wp, bp, gp, bep, B0, NV);

  // ---- layer 0: ic=64, H=4, hc=256, oc=256 ----
  gemm(B0, in(11), in(12), B1, NV, 64, 256);   // xl
  gemm(B0, in(13), in(14), B2, NV, 64, 256);   // xr
  gemm(B0, in(20), in(21), B3, NV, 64, 256);   // res
  build_csr(ei[0], ea[0]);
  aggregate_kernel<4><<<NV, 256, 0, stream>>>(
      ei[0], ea[0], easum, B1, B2, in(15), in(16), in(17), in(18), in(19),
      B3, counts, csr, B3, NE, NV);            // h1 = B3 [N,256]

  // ---- layer 1: ic=256, H=4, hc=256, oc=256 ----
  gemm(B3, in(22), in(23), B1, NV, 256, 256);  // xl
  gemm(B3, in(24), in(25), B2, NV, 256, 256);  // xr
  gemm(B3, in(31), in(32), B0, NV, 256, 256);  // res
  build_csr(ei[1], ea[1]);
  aggregate_kernel<4><<<NV, 256, 0, stream>>>(
      ei[1], ea[1], easum, B1, B2, in(26), in(27), in(28), in(29), in(30),
      B0, counts, csr, B0, NE, NV);            // h2 = B0 [N,256]

  // ---- layer 2: ic=256, H=1, hc=64, oc=64 ----
  gemm(B0, in(33), in(34), B1, NV, 256, 64);   // xl
  gemm(B0, in(35), in(36), B2, NV, 256, 64);   // xr
  gemm(B0, in(42), in(43), B3, NV, 256, 64);   // res
  build_csr(ei[2], ea[2]);
  aggregate_kernel<1><<<NV, 64, 0, stream>>>(
      ei[2], ea[2], easum, B1, B2, in(37), in(38), in(39), in(40), in(41),
      B3, counts, csr, (float*)d_out, NE, NV);
}

// Round 3
// 1474.356 us; speedup vs baseline: 1.0263x; 1.0263x over previous
//
#include <hip/hip_runtime.h>
#include <hip/hip_bf16.h>
#include <math.h>

#define NV 20000
#define NE 320000

typedef __attribute__((ext_vector_type(8))) short bf16x8;
typedef __attribute__((ext_vector_type(4))) float f32x4;

static __device__ __forceinline__ ushort f2b(float f) {
  __hip_bfloat16 h = __float2bfloat16(f);
  return *reinterpret_cast<ushort*>(&h);
}

// ---------------- proj: h0 = gelu(LN(x@Wp + bp; gp, bep)) -> bf16 ----------------
__global__ __launch_bounds__(256) void proj_kernel(
    const float* __restrict__ x, const float* __restrict__ Wp,
    const float* __restrict__ bp, const float* __restrict__ gp,
    const float* __restrict__ bep, ushort* __restrict__ h, int N)
{
  int wid = threadIdx.x >> 6, lane = threadIdx.x & 63;
  int row = blockIdx.x * 4 + wid;
  if (row >= N) return;
  float xv = x[(size_t)row * 64 + lane];
  float acc = bp[lane];
#pragma unroll
  for (int k = 0; k < 64; ++k) {
    float a = __shfl(xv, k, 64);
    acc = fmaf(a, Wp[k * 64 + lane], acc);
  }
  float s1 = acc, s2 = acc * acc;
#pragma unroll
  for (int o = 32; o; o >>= 1) { s1 += __shfl_xor(s1, o, 64); s2 += __shfl_xor(s2, o, 64); }
  float mean = s1 * (1.0f / 64.0f);
  float var  = s2 * (1.0f / 64.0f) - mean * mean;
  float y = (acc - mean) * rsqrtf(var + 1e-5f) * gp[lane] + bep[lane];
  float gel = 0.5f * y * (1.0f + erff(y * 0.70710678118654752f));
  h[(size_t)row * 64 + lane] = f2b(gel);
}

// ---------------- weight transpose-cast: WT[m][k] = bf16(W[k][m]) ----------------
struct CJob { const float* src; ushort* dst; int K, M; };
struct CJobs { CJob j[9]; };

__global__ __launch_bounds__(256) void cast_w_kernel(CJobs jobs) {
  CJob jb = jobs.j[blockIdx.y];
  const int total = jb.M * jb.K;
  for (int i = blockIdx.x * 256 + threadIdx.x; i < total; i += gridDim.x * 256) {
    int m = i / jb.K, k = i - m * jb.K;
    jb.dst[i] = f2b(jb.src[(size_t)k * jb.M + m]);
  }
}

// ---------------- bf16 MFMA GEMM: C[N,M] = A[N,K](bf16) @ W[K,M] + bias ----------------
// WT is [M][K] bf16. Tile 128x64, 256 thr (4 waves), wave w -> rows [w*32,w*32+32),
// K-tile 32, mfma_f32_16x16x32_bf16.
// Verified layouts: A[m=lane&15][k=(lane>>4)*8+j]; B[k=(lane>>4)*8+j][n=lane&15];
// C/D col=lane&15, row=(lane>>4)*4+reg.
__global__ __launch_bounds__(256) void gemm_mfma(
    const ushort* __restrict__ A, const ushort* __restrict__ WT,
    const float* __restrict__ bias, float* __restrict__ Cout,
    int N, int K, int M)
{
  __shared__ ushort As[128][40];
  __shared__ ushort Bs[64][40];
  const int t = threadIdx.x, wave = t >> 6, lane = t & 63;
  const int row0 = blockIdx.y * 128, col0 = blockIdx.x * 64;
  const int m_ = lane & 15, q = lane >> 4;
  f32x4 acc[2][4];
#pragma unroll
  for (int i = 0; i < 2; ++i)
#pragma unroll
    for (int j = 0; j < 4; ++j) acc[i][j] = (f32x4){0.f, 0.f, 0.f, 0.f};

  const int ar = t >> 1, ac = (t & 1) * 16;
  const int br = t >> 2, bcol = (t & 3) * 8;
  const ushort* Ap = A + (size_t)(row0 + ar) * K + ac;
  const ushort* Bp = WT + (size_t)(col0 + br) * K + bcol;
  const bool a_ok = (row0 + ar) < N;

  for (int k0 = 0; k0 < K; k0 += 32) {
    uint4 av0 = make_uint4(0, 0, 0, 0), av1 = make_uint4(0, 0, 0, 0);
    if (a_ok) { av0 = *(const uint4*)(Ap + k0); av1 = *(const uint4*)(Ap + k0 + 8); }
    uint4 bv = *(const uint4*)(Bp + k0);
    *(uint4*)&As[ar][ac] = av0;
    *(uint4*)&As[ar][ac + 8] = av1;
    *(uint4*)&Bs[br][bcol] = bv;
    __syncthreads();
    bf16x8 a0 = *(const bf16x8*)&As[wave * 32 + m_][q * 8];
    bf16x8 a1 = *(const bf16x8*)&As[wave * 32 + 16 + m_][q * 8];
#pragma unroll
    for (int cf = 0; cf < 4; ++cf) {
      bf16x8 b = *(const bf16x8*)&Bs[cf * 16 + m_][q * 8];
      acc[0][cf] = __builtin_amdgcn_mfma_f32_16x16x32_bf16(a0, b, acc[0][cf], 0, 0, 0);
      acc[1][cf] = __builtin_amdgcn_mfma_f32_16x16x32_bf16(a1, b, acc[1][cf], 0, 0, 0);
    }
    __syncthreads();
  }

#pragma unroll
  for (int rf = 0; rf < 2; ++rf) {
#pragma unroll
    for (int cf = 0; cf < 4; ++cf) {
      int col = col0 + cf * 16 + m_;
      float bb = bias[col];
#pragma unroll
      for (int r = 0; r < 4; ++r) {
        int row = row0 + wave * 32 + rf * 16 + q * 4 + r;
        if (row < N) Cout[(size_t)row * M + col] = acc[rf][cf][r] + bb;
      }
    }
  }
}

// ---------------- edge-attr column sums (for self-loop mean) ----------------
__global__ __launch_bounds__(256) void colsum_kernel(
    const float* __restrict__ ea, float* __restrict__ easum, int E)
{
  int t = threadIdx.x;
  int col = t & 15;
  int r = blockIdx.x * 16 + (t >> 4);
  int rstride = gridDim.x * 16;
  float s = 0.0f;
  for (; r < E; r += rstride) s += ea[(size_t)r * 16 + col];
  __shared__ float red[256];
  red[t] = s;
  __syncthreads();
  if (t < 16) {
    float tot = 0.0f;
    for (int j = t; j < 256; j += 16) tot += red[j];
    atomicAdd(&easum[t], tot);
  }
}

// ---------------- CSR build ----------------
__global__ __launch_bounds__(256) void hist_kernel(
    const int* __restrict__ ei, int* __restrict__ counts, int E, int total)
{
  int i = blockIdx.x * 256 + threadIdx.x;
  if (i >= total) return;
  int dst = (i < E) ? ei[E + i] : (i - E);
  atomicAdd(&counts[dst], 1);
}

__global__ __launch_bounds__(1024) void scan_kernel(
    int* __restrict__ counts, int* __restrict__ cursor, int N)
{
  __shared__ int wsum[16];
  __shared__ int running_s;
  int t = threadIdx.x;
  int lane = t & 63, wid = t >> 6;
  if (t == 0) running_s = 0;
  __syncthreads();
  for (int base = 0; base < N; base += 1024) {
    int i = base + t;
    int v = (i < N) ? counts[i] : 0;
    int x = v;
#pragma unroll
    for (int o = 1; o < 64; o <<= 1) {
      int y = __shfl_up(x, o, 64);
      if (lane >= o) x += y;
    }
    if (lane == 63) wsum[wid] = x;
    __syncthreads();
    int prefix = 0;
    for (int wj = 0; wj < wid; ++wj) prefix += wsum[wj];
    int run = running_s;
    int excl = run + prefix + x - v;
    if (i < N) { counts[i] = excl; cursor[i] = excl; }
    __syncthreads();
    if (t == 1023) running_s = run + prefix + x;
    __syncthreads();
  }
  if (t == 0) counts[N] = running_s;
}

__global__ __launch_bounds__(256) void scatter_kernel(
    const int* __restrict__ ei, int* __restrict__ cursor,
    int* __restrict__ csr, int E, int total)
{
  int i = blockIdx.x * 256 + threadIdx.x;
  if (i >= total) return;
  int dst = (i < E) ? ei[E + i] : (i - E);
  int pos = atomicAdd(&cursor[dst], 1);
  csr[pos] = i;
}

// ---------------- edge scores: wexp[e][h] = exp(att_h . lrelu(xl[src]+xr[dst]+ea@We)) ----------------
// Edge-parallel; indices [E, E+N) are self-loops (ea = column mean). Softmax max-shift
// dropped (scores are O(1) with these scales; exp cannot overflow).
template <int H>
__global__ __launch_bounds__(H * 64) void score_kernel(
    const int* __restrict__ ei, const float* __restrict__ ea,
    const float* __restrict__ easum, const float* __restrict__ We,
    const float* __restrict__ xl, const float* __restrict__ xr,
    const float* __restrict__ att, float* __restrict__ wexp,
    int E, int N)
{
  const int HC = H * 64;
  const int t = threadIdx.x, lane = t & 63, wave = t >> 6;
  float Wc[16];
#pragma unroll
  for (int k = 0; k < 16; ++k) Wc[k] = We[k * HC + t];
  const float att_t = att[t];
  float eself = 0.f;
#pragma unroll
  for (int k = 0; k < 16; ++k) eself = fmaf(easum[k], Wc[k], eself);
  eself *= 1.0f / (float)E;

  const int total = E + N;
  for (int e = blockIdx.x; e < total; e += gridDim.x) {
    int src, dst; float eev;
    if (e < E) {
      src = ei[e]; dst = ei[E + e];
      const float4* p = (const float4*)(ea + (size_t)e * 16);
      float4 q0 = p[0], q1 = p[1], q2 = p[2], q3 = p[3];
      eev = q0.x * Wc[0];
      eev = fmaf(q0.y, Wc[1], eev);  eev = fmaf(q0.z, Wc[2], eev);
      eev = fmaf(q0.w, Wc[3], eev);  eev = fmaf(q1.x, Wc[4], eev);
      eev = fmaf(q1.y, Wc[5], eev);  eev = fmaf(q1.z, Wc[6], eev);
      eev = fmaf(q1.w, Wc[7], eev);  eev = fmaf(q2.x, Wc[8], eev);
      eev = fmaf(q2.y, Wc[9], eev);  eev = fmaf(q2.z, Wc[10], eev);
      eev = fmaf(q2.w, Wc[11], eev); eev = fmaf(q3.x, Wc[12], eev);
      eev = fmaf(q3.y, Wc[13], eev); eev = fmaf(q3.z, Wc[14], eev);
      eev = fmaf(q3.w, Wc[15], eev);
    } else {
      src = dst = e - E;
      eev = eself;
    }
    float v = xl[(size_t)src * HC + t] + xr[(size_t)dst * HC + t] + eev;
    v = v > 0.f ? v : 0.2f * v;  // leaky_relu(0.2)
    float s = v * att_t;
#pragma unroll
    for (int o = 32; o; o >>= 1) s += __shfl_xor(s, o, 64);
    if (lane == 0) wexp[e * H + wave] = __expf(s);
  }
}

// ---------------- aggregate + epilogue (LN, gelu, +res) ----------------
// One block per dst node; wave = head, lane = channel.
template <int H>
__global__ __launch_bounds__(H * 64) void aggregate_kernel(
    const int* __restrict__ ei, const float* __restrict__ wexp,
    const float* __restrict__ xl, const float* __restrict__ bc,
    const float* __restrict__ g, const float* __restrict__ be,
    const float* __restrict__ res,
    const int* __restrict__ offs, const int* __restrict__ csr,
    float* __restrict__ houtf, ushort* __restrict__ houtb, int E)
{
  const int HC = H * 64;
  const int n = blockIdx.x, t = threadIdx.x, lane = t & 63, wave = t >> 6;
  float acc = 0.f, denom = 0.f;
  const int beg = offs[n], end = offs[n + 1];
  for (int idx = beg; idx < end; ++idx) {
    const int e = csr[idx];
    const int src = (e < E) ? ei[e] : n;
    const float w = wexp[e * H + wave];
    acc = fmaf(w, xl[(size_t)src * HC + t], acc);
    denom += w;
  }
  float out = acc / (denom + 1e-16f) + bc[t];

  // LayerNorm across HC channels
  float s1 = out, s2 = out * out;
#pragma unroll
  for (int o = 32; o; o >>= 1) { s1 += __shfl_xor(s1, o, 64); s2 += __shfl_xor(s2, o, 64); }
  if (H > 1) {
    __shared__ float r1[4], r2[4];
    if (lane == 0) { r1[wave] = s1; r2[wave] = s2; }
    __syncthreads();
    s1 = 0.f; s2 = 0.f;
#pragma unroll
    for (int j = 0; j < H; ++j) { s1 += r1[j]; s2 += r2[j]; }
  }
  float mean = s1 / (float)HC;
  float var  = s2 / (float)HC - mean * mean;
  float y = (out - mean) * rsqrtf(var + 1e-5f) * g[t] + be[t];
  float gel = 0.5f * y * (1.0f + erff(y * 0.70710678118654752f));
  float o = gel + res[(size_t)n * HC + t];
  if (houtf) houtf[(size_t)n * HC + t] = o;
  if (houtb) houtb[(size_t)n * HC + t] = f2b(o);
}

// ---------------- host launch ----------------
extern "C" void kernel_launch(void* const* d_in, const int* in_sizes, int n_in,
                              void* d_out, int out_size, void* d_ws, size_t ws_size,
                              hipStream_t stream)
{
  const float* x = (const float*)d_in[0];
  const int*   ei[3] = {(const int*)d_in[1], (const int*)d_in[3], (const int*)d_in[5]};
  const float* ea[3] = {(const float*)d_in[2], (const float*)d_in[4], (const float*)d_in[6]};
  const float* Wp  = (const float*)d_in[7];
  const float* bp  = (const float*)d_in[8];
  const float* gp  = (const float*)d_in[9];
  const float* bep = (const float*)d_in[10];
  auto in = [&](int i) { return (const float*)d_in[i]; };
  // per-layer base 11 + 11*i: Wl, bl, Wr, br, We, att, bc, g, be, Wsk, bsk

  const int ic[3] = {64, 256, 256}, hc[3] = {256, 256, 64}, oc[3] = {256, 256, 64};

  // ---- workspace layout (~93 MB; round-2's 273 MB overflowed d_ws) ----
  char* w = (char*)d_ws;
  size_t off = 0;
  auto alloc = [&](size_t bytes) { void* p = w + off; off = (off + bytes + 511) & ~(size_t)511; return p; };
  float*  B1   = (float*)alloc((size_t)NV * 256 * 4);   // xl (f32)
  float*  B2   = (float*)alloc((size_t)NV * 256 * 4);   // xr (f32)
  float*  B3   = (float*)alloc((size_t)NV * 256 * 4);   // res (f32)
  ushort* h0bf = (ushort*)alloc((size_t)NV * 64 * 2);
  ushort* h1bf = (ushort*)alloc((size_t)NV * 256 * 2);
  ushort* h2bf = (ushort*)alloc((size_t)NV * 256 * 2);
  ushort* WlT[3], *WrT[3], *WskT[3];
  for (int i = 0; i < 3; ++i) {
    WlT[i]  = (ushort*)alloc((size_t)hc[i] * ic[i] * 2);
    WrT[i]  = (ushort*)alloc((size_t)hc[i] * ic[i] * 2);
    WskT[i] = (ushort*)alloc((size_t)oc[i] * ic[i] * 2);
  }
  float* wexp   = (float*)alloc((size_t)(NE + NV) * 4 * 4);  // exp(score), [E+N][H]
  float* easum  = (float*)alloc(64);
  int*   counts = (int*)alloc((size_t)(NV + 1) * 4);   // memset covers easum pad + counts
  int*   cursor = (int*)alloc((size_t)NV * 4);
  int*   csr    = (int*)alloc((size_t)(NE + NV) * 4);

  // ---- weight transpose-casts (one launch) ----
  CJobs jobs;
  for (int i = 0; i < 3; ++i) {
    jobs.j[i * 3 + 0] = {in(11 + 11 * i), WlT[i],  ic[i], hc[i]};
    jobs.j[i * 3 + 1] = {in(13 + 11 * i), WrT[i],  ic[i], hc[i]};
    jobs.j[i * 3 + 2] = {in(20 + 11 * i), WskT[i], ic[i], oc[i]};
  }
  cast_w_kernel<<<dim3(16, 9), 256, 0, stream>>>(jobs);

  // ---- input projection -> h0bf [N,64] ----
  proj_kernel<<<(NV + 3) / 4, 256, 0, stream>>>(x, Wp, bp, gp, bep, h0bf, NV);

  auto gemm = [&](const ushort* A, const ushort* WT_, const float* b, float* C,
                  int N, int K, int M) {
    dim3 gsz(M / 64, (N + 127) / 128);
    gemm_mfma<<<gsz, 256, 0, stream>>>(A, WT_, b, C, N, K, M);
  };

  const ushort* hin[3] = {h0bf, h1bf, h2bf};
  ushort* hout_bf[3] = {h1bf, h2bf, nullptr};
  for (int i = 0; i < 3; ++i) {
    int K = ic[i], HCm = hc[i], OC = oc[i];
    gemm(hin[i], WlT[i],  in(12 + 11 * i), B1, NV, K, HCm);  // xl
    gemm(hin[i], WrT[i],  in(14 + 11 * i), B2, NV, K, HCm);  // xr
    gemm(hin[i], WskT[i], in(21 + 11 * i), B3, NV, K, OC);   // res
    hipMemsetAsync(easum, 0, 512 + (size_t)(NV + 1) * 4, stream);
    colsum_kernel<<<64, 256, 0, stream>>>(ea[i], easum, NE);
    hist_kernel<<<(NE + NV + 255) / 256, 256, 0, stream>>>(ei[i], counts, NE, NE + NV);
    scan_kernel<<<1, 1024, 0, stream>>>(counts, cursor, NV);
    scatter_kernel<<<(NE + NV + 255) / 256, 256, 0, stream>>>(ei[i], cursor, csr, NE, NE + NV);
    if (i < 2) {
      score_kernel<4><<<8192, 256, 0, stream>>>(
          ei[i], ea[i], easum, in(15 + 11 * i), B1, B2, in(16 + 11 * i),
          wexp, NE, NV);
      aggregate_kernel<4><<<NV, 256, 0, stream>>>(
          ei[i], wexp, B1, in(17 + 11 * i), in(18 + 11 * i), in(19 + 11 * i),
          B3, counts, csr, nullptr, hout_bf[i], NE);
    } else {
      score_kernel<1><<<8192, 64, 0, stream>>>(
          ei[i], ea[i], easum, in(15 + 11 * i), B1, B2, in(16 + 11 * i),
          wexp, NE, NV);
      aggregate_kernel<1><<<NV, 64, 0, stream>>>(
          ei[i], wexp, B1, in(17 + 11 * i), in(18 + 11 * i), in(19 + 11 * i),
          B3, counts, csr, (float*)d_out, nullptr, NE);
    }
  }
}

// Round 4
// 1279.601 us; speedup vs baseline: 1.1825x; 1.1522x over previous
//
#include <hip/hip_runtime.h>
#include <hip/hip_bf16.h>
#include <math.h>

#define NV 20000
#define NE 320000

typedef __attribute__((ext_vector_type(8))) short bf16x8;
typedef __attribute__((ext_vector_type(4))) float f32x4;

static __device__ __forceinline__ ushort f2b(float f) {
  __hip_bfloat16 h = __float2bfloat16(f);
  return *reinterpret_cast<ushort*>(&h);
}
static __device__ __forceinline__ float b2f(ushort u) {
  union { ushort s[2]; float f; } c;
  c.s[0] = 0; c.s[1] = u;
  return c.f;
}

// ---------------- proj: h0 = gelu(LN(x@Wp + bp; gp, bep)) -> bf16 ----------------
__global__ __launch_bounds__(256) void proj_kernel(
    const float* __restrict__ x, const float* __restrict__ Wp,
    const float* __restrict__ bp, const float* __restrict__ gp,
    const float* __restrict__ bep, ushort* __restrict__ h, int N)
{
  int wid = threadIdx.x >> 6, lane = threadIdx.x & 63;
  int row = blockIdx.x * 4 + wid;
  if (row >= N) return;
  float xv = x[(size_t)row * 64 + lane];
  float acc = bp[lane];
#pragma unroll
  for (int k = 0; k < 64; ++k) {
    float a = __shfl(xv, k, 64);
    acc = fmaf(a, Wp[k * 64 + lane], acc);
  }
  float s1 = acc, s2 = acc * acc;
#pragma unroll
  for (int o = 32; o; o >>= 1) { s1 += __shfl_xor(s1, o, 64); s2 += __shfl_xor(s2, o, 64); }
  float mean = s1 * (1.0f / 64.0f);
  float var  = s2 * (1.0f / 64.0f) - mean * mean;
  float y = (acc - mean) * rsqrtf(var + 1e-5f) * gp[lane] + bep[lane];
  float gel = 0.5f * y * (1.0f + erff(y * 0.70710678118654752f));
  h[(size_t)row * 64 + lane] = f2b(gel);
}

// ---------------- weight transpose-cast: WT[m][k] = bf16(W[k][m]) ----------------
struct CJob { const float* src; ushort* dst; int K, M; };
struct CJobs { CJob j[9]; };

__global__ __launch_bounds__(256) void cast_w_kernel(CJobs jobs) {
  CJob jb = jobs.j[blockIdx.y];
  const int total = jb.M * jb.K;
  for (int i = blockIdx.x * 256 + threadIdx.x; i < total; i += gridDim.x * 256) {
    int m = i / jb.K, k = i - m * jb.K;
    jb.dst[i] = f2b(jb.src[(size_t)k * jb.M + m]);
  }
}

// ---------------- bf16 MFMA GEMM: C[N,M] = A[N,K](bf16) @ W[K,M] + bias ----------------
// WT is [M][K] bf16. Tile 128x64, 256 thr (4 waves), wave w -> rows [w*32,w*32+32),
// K-tile 32, mfma_f32_16x16x32_bf16.
// Verified layouts: A[m=lane&15][k=(lane>>4)*8+j]; B[k=(lane>>4)*8+j][n=lane&15];
// C/D col=lane&15, row=(lane>>4)*4+reg.
template <bool OUT_BF16>
__global__ __launch_bounds__(256) void gemm_mfma(
    const ushort* __restrict__ A, const ushort* __restrict__ WT,
    const float* __restrict__ bias, void* __restrict__ Cout,
    int N, int K, int M)
{
  __shared__ ushort As[128][40];
  __shared__ ushort Bs[64][40];
  const int t = threadIdx.x, wave = t >> 6, lane = t & 63;
  const int row0 = blockIdx.y * 128, col0 = blockIdx.x * 64;
  const int m_ = lane & 15, q = lane >> 4;
  f32x4 acc[2][4];
#pragma unroll
  for (int i = 0; i < 2; ++i)
#pragma unroll
    for (int j = 0; j < 4; ++j) acc[i][j] = (f32x4){0.f, 0.f, 0.f, 0.f};

  const int ar = t >> 1, ac = (t & 1) * 16;
  const int br = t >> 2, bcol = (t & 3) * 8;
  const ushort* Ap = A + (size_t)(row0 + ar) * K + ac;
  const ushort* Bp = WT + (size_t)(col0 + br) * K + bcol;
  const bool a_ok = (row0 + ar) < N;

  for (int k0 = 0; k0 < K; k0 += 32) {
    uint4 av0 = make_uint4(0, 0, 0, 0), av1 = make_uint4(0, 0, 0, 0);
    if (a_ok) { av0 = *(const uint4*)(Ap + k0); av1 = *(const uint4*)(Ap + k0 + 8); }
    uint4 bv = *(const uint4*)(Bp + k0);
    *(uint4*)&As[ar][ac] = av0;
    *(uint4*)&As[ar][ac + 8] = av1;
    *(uint4*)&Bs[br][bcol] = bv;
    __syncthreads();
    bf16x8 a0 = *(const bf16x8*)&As[wave * 32 + m_][q * 8];
    bf16x8 a1 = *(const bf16x8*)&As[wave * 32 + 16 + m_][q * 8];
#pragma unroll
    for (int cf = 0; cf < 4; ++cf) {
      bf16x8 b = *(const bf16x8*)&Bs[cf * 16 + m_][q * 8];
      acc[0][cf] = __builtin_amdgcn_mfma_f32_16x16x32_bf16(a0, b, acc[0][cf], 0, 0, 0);
      acc[1][cf] = __builtin_amdgcn_mfma_f32_16x16x32_bf16(a1, b, acc[1][cf], 0, 0, 0);
    }
    __syncthreads();
  }

#pragma unroll
  for (int rf = 0; rf < 2; ++rf) {
#pragma unroll
    for (int cf = 0; cf < 4; ++cf) {
      int col = col0 + cf * 16 + m_;
      float bb = bias[col];
#pragma unroll
      for (int r = 0; r < 4; ++r) {
        int row = row0 + wave * 32 + rf * 16 + q * 4 + r;
        if (row < N) {
          float v = acc[rf][cf][r] + bb;
          if (OUT_BF16) ((ushort*)Cout)[(size_t)row * M + col] = f2b(v);
          else          ((float*)Cout)[(size_t)row * M + col] = v;
        }
      }
    }
  }
}

// ---------------- edge-attr column sums (for self-loop mean) ----------------
__global__ __launch_bounds__(256) void colsum_kernel(
    const float* __restrict__ ea, float* __restrict__ easum, int E)
{
  int t = threadIdx.x;
  int col = t & 15;
  int r = blockIdx.x * 16 + (t >> 4);
  int rstride = gridDim.x * 16;
  float s = 0.0f;
  for (; r < E; r += rstride) s += ea[(size_t)r * 16 + col];
  __shared__ float red[256];
  red[t] = s;
  __syncthreads();
  if (t < 16) {
    float tot = 0.0f;
    for (int j = t; j < 256; j += 16) tot += red[j];
    atomicAdd(&easum[t], tot);
  }
}

// ---------------- CSR build ----------------
__global__ __launch_bounds__(256) void hist_kernel(
    const int* __restrict__ ei, int* __restrict__ counts, int E, int total)
{
  int i = blockIdx.x * 256 + threadIdx.x;
  if (i >= total) return;
  int dst = (i < E) ? ei[E + i] : (i - E);
  atomicAdd(&counts[dst], 1);
}

__global__ __launch_bounds__(1024) void scan_kernel(
    int* __restrict__ counts, int* __restrict__ cursor, int N)
{
  __shared__ int wsum[16];
  __shared__ int running_s;
  int t = threadIdx.x;
  int lane = t & 63, wid = t >> 6;
  if (t == 0) running_s = 0;
  __syncthreads();
  for (int base = 0; base < N; base += 1024) {
    int i = base + t;
    int v = (i < N) ? counts[i] : 0;
    int x = v;
#pragma unroll
    for (int o = 1; o < 64; o <<= 1) {
      int y = __shfl_up(x, o, 64);
      if (lane >= o) x += y;
    }
    if (lane == 63) wsum[wid] = x;
    __syncthreads();
    int prefix = 0;
    for (int wj = 0; wj < wid; ++wj) prefix += wsum[wj];
    int run = running_s;
    int excl = run + prefix + x - v;
    if (i < N) { counts[i] = excl; cursor[i] = excl; }
    __syncthreads();
    if (t == 1023) running_s = run + prefix + x;
    __syncthreads();
  }
  if (t == 0) counts[N] = running_s;
}

__global__ __launch_bounds__(256) void scatter_kernel(
    const int* __restrict__ ei, int* __restrict__ cursor,
    int* __restrict__ csr, int E, int total)
{
  int i = blockIdx.x * 256 + threadIdx.x;
  if (i >= total) return;
  int dst = (i < E) ? ei[E + i] : (i - E);
  int pos = atomicAdd(&cursor[dst], 1);
  csr[pos] = i;
}

// ---------------- fused GATv2: score + softmax + aggregate + LN + gelu + res ----------------
// One block per dst node; wave = head, lane = channel. xl/xr in bf16 (halves the
// random-gather bytes that bound round 3's score_kernel); xr read ONCE per node;
// xl[src] read once per edge and reused for score + accumulate.
template <int H>
__global__ __launch_bounds__(H * 64) void fused_agg_kernel(
    const int* __restrict__ ei, const float* __restrict__ ea,
    const float* __restrict__ easum, const float* __restrict__ We,
    const ushort* __restrict__ xl, const ushort* __restrict__ xr,
    const float* __restrict__ att, const float* __restrict__ bc,
    const float* __restrict__ g, const float* __restrict__ be,
    const float* __restrict__ res,
    const int* __restrict__ offs, const int* __restrict__ csr,
    float* __restrict__ houtf, ushort* __restrict__ houtb, int E)
{
  const int HC = H * 64;
  const int n = blockIdx.x, t = threadIdx.x, lane = t & 63, wave = t >> 6;
  const float xr_t = b2f(xr[(size_t)n * HC + t]);
  const float att_t = att[t];
  float Wc[16];
#pragma unroll
  for (int k = 0; k < 16; ++k) Wc[k] = We[k * HC + t];
  float eself = 0.f;
#pragma unroll
  for (int k = 0; k < 16; ++k) eself = fmaf(easum[k], Wc[k], eself);
  eself *= 1.0f / (float)E;

  float acc = 0.f, denom = 0.f;
  const int beg = offs[n], end = offs[n + 1];
  for (int idx = beg; idx < end; ++idx) {
    const int e = csr[idx];
    int src; float eev;
    if (e < E) {
      src = ei[e];
      // ea row: wave-uniform address -> broadcast from L1
      const float4* p = (const float4*)(ea + (size_t)e * 16);
      float4 q0 = p[0], q1 = p[1], q2 = p[2], q3 = p[3];
      eev = q0.x * Wc[0];
      eev = fmaf(q0.y, Wc[1], eev);  eev = fmaf(q0.z, Wc[2], eev);
      eev = fmaf(q0.w, Wc[3], eev);  eev = fmaf(q1.x, Wc[4], eev);
      eev = fmaf(q1.y, Wc[5], eev);  eev = fmaf(q1.z, Wc[6], eev);
      eev = fmaf(q1.w, Wc[7], eev);  eev = fmaf(q2.x, Wc[8], eev);
      eev = fmaf(q2.y, Wc[9], eev);  eev = fmaf(q2.z, Wc[10], eev);
      eev = fmaf(q2.w, Wc[11], eev); eev = fmaf(q3.x, Wc[12], eev);
      eev = fmaf(q3.y, Wc[13], eev); eev = fmaf(q3.z, Wc[14], eev);
      eev = fmaf(q3.w, Wc[15], eev);
    } else {
      src = n;      // self loop
      eev = eself;
    }
    const float xls = b2f(xl[(size_t)src * HC + t]);
    float v = xls + xr_t + eev;
    v = v > 0.f ? v : 0.2f * v;  // leaky_relu(0.2)
    float s = v * att_t;
#pragma unroll
    for (int o = 32; o; o >>= 1) s += __shfl_xor(s, o, 64);
    const float w = __expf(s);
    acc = fmaf(w, xls, acc);
    denom += w;
  }
  float out = acc / (denom + 1e-16f) + bc[t];

  // LayerNorm across HC channels
  float s1 = out, s2 = out * out;
#pragma unroll
  for (int o = 32; o; o >>= 1) { s1 += __shfl_xor(s1, o, 64); s2 += __shfl_xor(s2, o, 64); }
  if (H > 1) {
    __shared__ float r1[4], r2[4];
    if (lane == 0) { r1[wave] = s1; r2[wave] = s2; }
    __syncthreads();
    s1 = 0.f; s2 = 0.f;
#pragma unroll
    for (int j = 0; j < H; ++j) { s1 += r1[j]; s2 += r2[j]; }
  }
  float mean = s1 / (float)HC;
  float var  = s2 / (float)HC - mean * mean;
  float y = (out - mean) * rsqrtf(var + 1e-5f) * g[t] + be[t];
  float gel = 0.5f * y * (1.0f + erff(y * 0.70710678118654752f));
  float o = gel + res[(size_t)n * HC + t];
  if (houtf) houtf[(size_t)n * HC + t] = o;
  if (houtb) houtb[(size_t)n * HC + t] = f2b(o);
}

// ---------------- host launch ----------------
extern "C" void kernel_launch(void* const* d_in, const int* in_sizes, int n_in,
                              void* d_out, int out_size, void* d_ws, size_t ws_size,
                              hipStream_t stream)
{
  const float* x = (const float*)d_in[0];
  const int*   ei[3] = {(const int*)d_in[1], (const int*)d_in[3], (const int*)d_in[5]};
  const float* ea[3] = {(const float*)d_in[2], (const float*)d_in[4], (const float*)d_in[6]};
  const float* Wp  = (const float*)d_in[7];
  const float* bp  = (const float*)d_in[8];
  const float* gp  = (const float*)d_in[9];
  const float* bep = (const float*)d_in[10];
  auto in = [&](int i) { return (const float*)d_in[i]; };
  // per-layer base 11 + 11*i: Wl, bl, Wr, br, We, att, bc, g, be, Wsk, bsk

  const int ic[3] = {64, 256, 256}, hc[3] = {256, 256, 64}, oc[3] = {256, 256, 64};

  // ---- workspace layout (~75 MB) ----
  char* w = (char*)d_ws;
  size_t off = 0;
  auto alloc = [&](size_t bytes) { void* p = w + off; off = (off + bytes + 511) & ~(size_t)511; return p; };
  ushort* B1   = (ushort*)alloc((size_t)NV * 256 * 2);  // xl (bf16)
  ushort* B2   = (ushort*)alloc((size_t)NV * 256 * 2);  // xr (bf16)
  float*  B3   = (float*)alloc((size_t)NV * 256 * 4);   // res (f32)
  ushort* h0bf = (ushort*)alloc((size_t)NV * 64 * 2);
  ushort* h1bf = (ushort*)alloc((size_t)NV * 256 * 2);
  ushort* h2bf = (ushort*)alloc((size_t)NV * 256 * 2);
  ushort* WlT[3], *WrT[3], *WskT[3];
  for (int i = 0; i < 3; ++i) {
    WlT[i]  = (ushort*)alloc((size_t)hc[i] * ic[i] * 2);
    WrT[i]  = (ushort*)alloc((size_t)hc[i] * ic[i] * 2);
    WskT[i] = (ushort*)alloc((size_t)oc[i] * ic[i] * 2);
  }
  float* easum  = (float*)alloc(64);
  int*   counts = (int*)alloc((size_t)(NV + 1) * 4);   // memset covers easum pad + counts
  int*   cursor = (int*)alloc((size_t)NV * 4);
  int*   csr    = (int*)alloc((size_t)(NE + NV) * 4);

  // ---- weight transpose-casts (one launch) ----
  CJobs jobs;
  for (int i = 0; i < 3; ++i) {
    jobs.j[i * 3 + 0] = {in(11 + 11 * i), WlT[i],  ic[i], hc[i]};
    jobs.j[i * 3 + 1] = {in(13 + 11 * i), WrT[i],  ic[i], hc[i]};
    jobs.j[i * 3 + 2] = {in(20 + 11 * i), WskT[i], ic[i], oc[i]};
  }
  cast_w_kernel<<<dim3(16, 9), 256, 0, stream>>>(jobs);

  // ---- input projection -> h0bf [N,64] ----
  proj_kernel<<<(NV + 3) / 4, 256, 0, stream>>>(x, Wp, bp, gp, bep, h0bf, NV);

  auto gemm_bf = [&](const ushort* A, const ushort* WT_, const float* b, ushort* C,
                     int N, int K, int M) {
    dim3 gsz(M / 64, (N + 127) / 128);
    gemm_mfma<true><<<gsz, 256, 0, stream>>>(A, WT_, b, C, N, K, M);
  };
  auto gemm_f32 = [&](const ushort* A, const ushort* WT_, const float* b, float* C,
                      int N, int K, int M) {
    dim3 gsz(M / 64, (N + 127) / 128);
    gemm_mfma<false><<<gsz, 256, 0, stream>>>(A, WT_, b, C, N, K, M);
  };

  const ushort* hin[3] = {h0bf, h1bf, h2bf};
  ushort* hout_bf[3] = {h1bf, h2bf, nullptr};
  for (int i = 0; i < 3; ++i) {
    int K = ic[i], HCm = hc[i], OC = oc[i];
    gemm_bf (hin[i], WlT[i],  in(12 + 11 * i), B1, NV, K, HCm);  // xl (bf16)
    gemm_bf (hin[i], WrT[i],  in(14 + 11 * i), B2, NV, K, HCm);  // xr (bf16)
    gemm_f32(hin[i], WskT[i], in(21 + 11 * i), B3, NV, K, OC);   // res (f32)
    hipMemsetAsync(easum, 0, 512 + (size_t)(NV + 1) * 4, stream);
    colsum_kernel<<<64, 256, 0, stream>>>(ea[i], easum, NE);
    hist_kernel<<<(NE + NV + 255) / 256, 256, 0, stream>>>(ei[i], counts, NE, NE + NV);
    scan_kernel<<<1, 1024, 0, stream>>>(counts, cursor, NV);
    scatter_kernel<<<(NE + NV + 255) / 256, 256, 0, stream>>>(ei[i], cursor, csr, NE, NE + NV);
    if (i < 2) {
      fused_agg_kernel<4><<<NV, 256, 0, stream>>>(
          ei[i], ea[i], easum, in(15 + 11 * i), B1, B2, in(16 + 11 * i),
          in(17 + 11 * i), in(18 + 11 * i), in(19 + 11 * i), B3,
          counts, csr, nullptr, hout_bf[i], NE);
    } else {
      fused_agg_kernel<1><<<NV, 64, 0, stream>>>(
          ei[i], ea[i], easum, in(15 + 11 * i), B1, B2, in(16 + 11 * i),
          in(17 + 11 * i), in(18 + 11 * i), in(19 + 11 * i), B3,
          counts, csr, (float*)d_out, nullptr, NE);
    }
  }
}

// Round 5
// 1051.576 us; speedup vs baseline: 1.4389x; 1.2168x over previous
//
#include <hip/hip_runtime.h>
#include <hip/hip_bf16.h>
#include <math.h>

#define NV 20000
#define NE 320000

typedef __attribute__((ext_vector_type(8))) short bf16x8;
typedef __attribute__((ext_vector_type(4))) float f32x4;

static __device__ __forceinline__ ushort f2b(float f) {
  __hip_bfloat16 h = __float2bfloat16(f);
  return *reinterpret_cast<ushort*>(&h);
}
static __device__ __forceinline__ float b2f(ushort u) {
  union { ushort s[2]; float f; } c;
  c.s[0] = 0; c.s[1] = u;
  return c.f;
}

// DPP wave-64 sum: 6 VALU adds (vs 6 DS shuffle ops), result broadcast via readlane.
// Sequence: row_shr 1/2/4/8 (row sums in lane 15 of each 16-row), row_bcast15 to rows
// 1&3, row_bcast31 to rows 2&3 -> lane 63 holds the full sum.
static __device__ __forceinline__ float wave_sum64(float x) {
  x += __int_as_float(__builtin_amdgcn_update_dpp(0, __float_as_int(x), 0x111, 0xF, 0xF, true));
  x += __int_as_float(__builtin_amdgcn_update_dpp(0, __float_as_int(x), 0x112, 0xF, 0xF, true));
  x += __int_as_float(__builtin_amdgcn_update_dpp(0, __float_as_int(x), 0x114, 0xF, 0xF, true));
  x += __int_as_float(__builtin_amdgcn_update_dpp(0, __float_as_int(x), 0x118, 0xF, 0xF, true));
  x += __int_as_float(__builtin_amdgcn_update_dpp(0, __float_as_int(x), 0x142, 0xA, 0xF, true));
  x += __int_as_float(__builtin_amdgcn_update_dpp(0, __float_as_int(x), 0x143, 0xC, 0xF, true));
  return __int_as_float(__builtin_amdgcn_readlane(__float_as_int(x), 63));
}

// ---------------- proj: h0 = gelu(LN(x@Wp + bp; gp, bep)) -> bf16 ----------------
__global__ __launch_bounds__(256) void proj_kernel(
    const float* __restrict__ x, const float* __restrict__ Wp,
    const float* __restrict__ bp, const float* __restrict__ gp,
    const float* __restrict__ bep, ushort* __restrict__ h, int N)
{
  int wid = threadIdx.x >> 6, lane = threadIdx.x & 63;
  int row = blockIdx.x * 4 + wid;
  if (row >= N) return;
  float xv = x[(size_t)row * 64 + lane];
  float acc = bp[lane];
#pragma unroll
  for (int k = 0; k < 64; ++k) {
    float a = __shfl(xv, k, 64);
    acc = fmaf(a, Wp[k * 64 + lane], acc);
  }
  float s1 = wave_sum64(acc), s2 = wave_sum64(acc * acc);
  float mean = s1 * (1.0f / 64.0f);
  float var  = s2 * (1.0f / 64.0f) - mean * mean;
  float y = (acc - mean) * rsqrtf(var + 1e-5f) * gp[lane] + bep[lane];
  float gel = 0.5f * y * (1.0f + erff(y * 0.70710678118654752f));
  h[(size_t)row * 64 + lane] = f2b(gel);
}

// ---------------- weight transpose-cast: WT[m][k] = bf16(W[k][m]) ----------------
struct CJob { const float* src; ushort* dst; int K, M; };
struct CJobs { CJob j[9]; };

__global__ __launch_bounds__(256) void cast_w_kernel(CJobs jobs) {
  CJob jb = jobs.j[blockIdx.y];
  const int total = jb.M * jb.K;
  for (int i = blockIdx.x * 256 + threadIdx.x; i < total; i += gridDim.x * 256) {
    int m = i / jb.K, k = i - m * jb.K;
    jb.dst[i] = f2b(jb.src[(size_t)k * jb.M + m]);
  }
}

// ---------------- fused per-layer GEMM: [xl | xr | res] = A @ [Wl|Wr|Wsk] + bias ----------------
// WT is [Mtot][K] bf16 (concat of transposed Wl, Wr, Wsk). Tile 128x64, 4 waves,
// mfma_f32_16x16x32_bf16. Segments (all 64-aligned): [0,M1) -> O0 bf16 (xl),
// [M1,M2) -> O1 bf16 (xr), [M2,Mtot) -> O2 f32 (res).
__global__ __launch_bounds__(256) void gemm_fused(
    const ushort* __restrict__ A, const ushort* __restrict__ WT,
    const float* __restrict__ b0, const float* __restrict__ b1,
    const float* __restrict__ b2,
    ushort* __restrict__ O0, ushort* __restrict__ O1, float* __restrict__ O2,
    int N, int K, int M1, int M2, int Mtot)
{
  __shared__ ushort As[128][40];
  __shared__ ushort Bs[64][40];
  const int t = threadIdx.x, wave = t >> 6, lane = t & 63;
  const int row0 = blockIdx.y * 128, col0 = blockIdx.x * 64;
  const int m_ = lane & 15, q = lane >> 4;
  f32x4 acc[2][4];
#pragma unroll
  for (int i = 0; i < 2; ++i)
#pragma unroll
    for (int j = 0; j < 4; ++j) acc[i][j] = (f32x4){0.f, 0.f, 0.f, 0.f};

  const int ar = t >> 1, ac = (t & 1) * 16;
  const int br = t >> 2, bcol = (t & 3) * 8;
  const ushort* Ap = A + (size_t)(row0 + ar) * K + ac;
  const ushort* Bp = WT + (size_t)(col0 + br) * K + bcol;
  const bool a_ok = (row0 + ar) < N;

  for (int k0 = 0; k0 < K; k0 += 32) {
    uint4 av0 = make_uint4(0, 0, 0, 0), av1 = make_uint4(0, 0, 0, 0);
    if (a_ok) { av0 = *(const uint4*)(Ap + k0); av1 = *(const uint4*)(Ap + k0 + 8); }
    uint4 bv = *(const uint4*)(Bp + k0);
    *(uint4*)&As[ar][ac] = av0;
    *(uint4*)&As[ar][ac + 8] = av1;
    *(uint4*)&Bs[br][bcol] = bv;
    __syncthreads();
    bf16x8 a0 = *(const bf16x8*)&As[wave * 32 + m_][q * 8];
    bf16x8 a1 = *(const bf16x8*)&As[wave * 32 + 16 + m_][q * 8];
#pragma unroll
    for (int cf = 0; cf < 4; ++cf) {
      bf16x8 b = *(const bf16x8*)&Bs[cf * 16 + m_][q * 8];
      acc[0][cf] = __builtin_amdgcn_mfma_f32_16x16x32_bf16(a0, b, acc[0][cf], 0, 0, 0);
      acc[1][cf] = __builtin_amdgcn_mfma_f32_16x16x32_bf16(a1, b, acc[1][cf], 0, 0, 0);
    }
    __syncthreads();
  }

  // segmented epilogue (whole 64-wide tile lies in one segment)
  const float* bias; int base, mode, Wd;
  if (col0 < M1)      { bias = b0; base = 0;  mode = 0; Wd = M1; }
  else if (col0 < M2) { bias = b1; base = M1; mode = 1; Wd = M2 - M1; }
  else                { bias = b2; base = M2; mode = 2; Wd = Mtot - M2; }

#pragma unroll
  for (int rf = 0; rf < 2; ++rf) {
#pragma unroll
    for (int cf = 0; cf < 4; ++cf) {
      int col = col0 + cf * 16 + m_ - base;
      float bb = bias[col];
#pragma unroll
      for (int r = 0; r < 4; ++r) {
        int row = row0 + wave * 32 + rf * 16 + q * 4 + r;
        if (row < N) {
          float v = acc[rf][cf][r] + bb;
          if (mode == 0)      O0[(size_t)row * Wd + col] = f2b(v);
          else if (mode == 1) O1[(size_t)row * Wd + col] = f2b(v);
          else                O2[(size_t)row * Wd + col] = v;
        }
      }
    }
  }
}

// ---------------- edge-attr column sums (for self-loop mean) ----------------
__global__ __launch_bounds__(256) void colsum_kernel(
    const float* __restrict__ ea, float* __restrict__ easum, int E)
{
  int t = threadIdx.x;
  int col = t & 15;
  int r = blockIdx.x * 16 + (t >> 4);
  int rstride = gridDim.x * 16;
  float s = 0.0f;
  for (; r < E; r += rstride) s += ea[(size_t)r * 16 + col];
  __shared__ float red[256];
  red[t] = s;
  __syncthreads();
  if (t < 16) {
    float tot = 0.0f;
    for (int j = t; j < 256; j += 16) tot += red[j];
    atomicAdd(&easum[t], tot);
  }
}

// ---------------- CSR build ----------------
__global__ __launch_bounds__(256) void hist_kernel(
    const int* __restrict__ ei, int* __restrict__ counts, int E, int total)
{
  int i = blockIdx.x * 256 + threadIdx.x;
  if (i >= total) return;
  int dst = (i < E) ? ei[E + i] : (i - E);
  atomicAdd(&counts[dst], 1);
}

// single-block scan, 20 elems/thread (1024*20 >= N+1), 2 barriers total
__global__ __launch_bounds__(1024) void scan_kernel(
    int* __restrict__ counts, int* __restrict__ cursor, int N)
{
  __shared__ int ws[16];
  __shared__ int wexcl[17];
  const int t = threadIdx.x, lane = t & 63, wid = t >> 6;
  const int base = t * 20;
  int v[20];
  int tot = 0;
#pragma unroll
  for (int j = 0; j < 20; ++j) {
    int i = base + j;
    v[j] = (i < N) ? counts[i] : 0;
    tot += v[j];
  }
  int x = tot;
#pragma unroll
  for (int o = 1; o < 64; o <<= 1) {
    int y = __shfl_up(x, o, 64);
    if (lane >= o) x += y;
  }
  if (lane == 63) ws[wid] = x;
  __syncthreads();
  if (t == 0) {
    int r = 0;
#pragma unroll
    for (int j = 0; j < 16; ++j) { wexcl[j] = r; r += ws[j]; }
    wexcl[16] = r;
  }
  __syncthreads();
  int run = wexcl[wid] + (x - tot);
#pragma unroll
  for (int j = 0; j < 20; ++j) {
    int i = base + j;
    if (i < N) { counts[i] = run; cursor[i] = run; }
    run += v[j];
  }
  if (t == 0) counts[N] = wexcl[16];
}

// scatter (src, edge_id) pairs — removes the ei[e] indirection from the hot loop
__global__ __launch_bounds__(256) void scatter_kernel(
    const int* __restrict__ ei, int* __restrict__ cursor,
    uint2* __restrict__ csr2, int E, int total)
{
  int i = blockIdx.x * 256 + threadIdx.x;
  if (i >= total) return;
  int dst, src;
  if (i < E) { dst = ei[E + i]; src = ei[i]; }
  else       { dst = i - E;     src = i - E; }
  int pos = atomicAdd(&cursor[dst], 1);
  csr2[pos] = make_uint2((unsigned)src, (unsigned)i);
}

// ---------------- fused GATv2: score + softmax + aggregate + LN + gelu + res ----------------
// H=4: one block (4 waves) per node, wave = head, lane = channel.
// H=1: one wave per node, 4 nodes per 256-thr block.
// 2-edge ILP per iteration + csr2-pair prefetch + DPP reductions.
template <int H>
__global__ __launch_bounds__(256) void fused_agg_kernel(
    const float* __restrict__ ea, const float* __restrict__ easum,
    const float* __restrict__ We,
    const ushort* __restrict__ xl, const ushort* __restrict__ xr,
    const float* __restrict__ att, const float* __restrict__ bc,
    const float* __restrict__ g, const float* __restrict__ be,
    const float* __restrict__ res,
    const int* __restrict__ offs, const uint2* __restrict__ csr2,
    float* __restrict__ houtf, ushort* __restrict__ houtb, int E)
{
  const int HC = H * 64;
  const int t = threadIdx.x, lane = t & 63, wave = t >> 6;
  const int n = (H == 1) ? blockIdx.x * 4 + wave : blockIdx.x;
  const int c = (H == 1) ? lane : t;

  const float xr_t = b2f(xr[(size_t)n * HC + c]);
  const float att_t = att[c];
  float Wc[16];
#pragma unroll
  for (int k = 0; k < 16; ++k) Wc[k] = We[k * HC + c];
  float eself = 0.f;
#pragma unroll
  for (int k = 0; k < 16; ++k) eself = fmaf(easum[k], Wc[k], eself);
  eself *= 1.0f / (float)E;

  float acc = 0.f, denom = 0.f;
  const int beg = offs[n], end = offs[n + 1];
  const int last = end - 1;  // every node has >=1 entry (self loop)

  uint2 P0 = csr2[beg];
  uint2 P1 = csr2[min(beg + 1, last)];
  for (int idx = beg; idx < end; idx += 2) {
    uint2 Q0 = csr2[min(idx + 2, last)];
    uint2 Q1 = csr2[min(idx + 3, last)];
    const int valid1 = (idx + 1 < end);
    const int src0 = (int)P0.x, e0 = (int)P0.y;
    const int src1 = (int)P1.x, e1 = (int)P1.y;

    const float4* r0 = (const float4*)(ea + (size_t)min(e0, E - 1) * 16);
    const float4* r1 = (const float4*)(ea + (size_t)min(e1, E - 1) * 16);
    float4 a0 = r0[0], a1 = r0[1], a2 = r0[2], a3 = r0[3];
    float4 b0 = r1[0], b1 = r1[1], b2 = r1[2], b3 = r1[3];
    const float xls0 = b2f(xl[(size_t)src0 * HC + c]);
    const float xls1 = b2f(xl[(size_t)src1 * HC + c]);

    float ee0 = a0.x * Wc[0];
    ee0 = fmaf(a0.y, Wc[1], ee0);  ee0 = fmaf(a0.z, Wc[2], ee0);
    ee0 = fmaf(a0.w, Wc[3], ee0);  ee0 = fmaf(a1.x, Wc[4], ee0);
    ee0 = fmaf(a1.y, Wc[5], ee0);  ee0 = fmaf(a1.z, Wc[6], ee0);
    ee0 = fmaf(a1.w, Wc[7], ee0);  ee0 = fmaf(a2.x, Wc[8], ee0);
    ee0 = fmaf(a2.y, Wc[9], ee0);  ee0 = fmaf(a2.z, Wc[10], ee0);
    ee0 = fmaf(a2.w, Wc[11], ee0); ee0 = fmaf(a3.x, Wc[12], ee0);
    ee0 = fmaf(a3.y, Wc[13], ee0); ee0 = fmaf(a3.z, Wc[14], ee0);
    ee0 = fmaf(a3.w, Wc[15], ee0);
    if (e0 >= E) ee0 = eself;

    float ee1 = b0.x * Wc[0];
    ee1 = fmaf(b0.y, Wc[1], ee1);  ee1 = fmaf(b0.z, Wc[2], ee1);
    ee1 = fmaf(b0.w, Wc[3], ee1);  ee1 = fmaf(b1.x, Wc[4], ee1);
    ee1 = fmaf(b1.y, Wc[5], ee1);  ee1 = fmaf(b1.z, Wc[6], ee1);
    ee1 = fmaf(b1.w, Wc[7], ee1);  ee1 = fmaf(b2.x, Wc[8], ee1);
    ee1 = fmaf(b2.y, Wc[9], ee1);  ee1 = fmaf(b2.z, Wc[10], ee1);
    ee1 = fmaf(b2.w, Wc[11], ee1); ee1 = fmaf(b3.x, Wc[12], ee1);
    ee1 = fmaf(b3.y, Wc[13], ee1); ee1 = fmaf(b3.z, Wc[14], ee1);
    ee1 = fmaf(b3.w, Wc[15], ee1);
    if (e1 >= E) ee1 = eself;

    float v0 = xls0 + xr_t + ee0;
    v0 = v0 > 0.f ? v0 : 0.2f * v0;
    float v1 = xls1 + xr_t + ee1;
    v1 = v1 > 0.f ? v1 : 0.2f * v1;
    const float S0 = wave_sum64(v0 * att_t);
    const float S1 = wave_sum64(v1 * att_t);
    const float w0 = __expf(S0);
    const float w1 = valid1 ? __expf(S1) : 0.f;
    acc = fmaf(w0, xls0, acc); denom += w0;
    acc = fmaf(w1, xls1, acc); denom += w1;
    P0 = Q0; P1 = Q1;
  }

  float out = acc / (denom + 1e-16f) + bc[c];

  // LayerNorm across HC channels
  float s1 = wave_sum64(out), s2 = wave_sum64(out * out);
  if (H > 1) {
    __shared__ float r1s[4], r2s[4];
    if (lane == 0) { r1s[wave] = s1; r2s[wave] = s2; }
    __syncthreads();
    s1 = 0.f; s2 = 0.f;
#pragma unroll
    for (int j = 0; j < H; ++j) { s1 += r1s[j]; s2 += r2s[j]; }
  }
  float mean = s1 / (float)HC;
  float var  = s2 / (float)HC - mean * mean;
  float y = (out - mean) * rsqrtf(var + 1e-5f) * g[c] + be[c];
  float gel = 0.5f * y * (1.0f + erff(y * 0.70710678118654752f));
  float o = gel + res[(size_t)n * HC + c];
  if (houtf) houtf[(size_t)n * HC + c] = o;
  if (houtb) houtb[(size_t)n * HC + c] = f2b(o);
}

// ---------------- host launch ----------------
extern "C" void kernel_launch(void* const* d_in, const int* in_sizes, int n_in,
                              void* d_out, int out_size, void* d_ws, size_t ws_size,
                              hipStream_t stream)
{
  const float* x = (const float*)d_in[0];
  const int*   ei[3] = {(const int*)d_in[1], (const int*)d_in[3], (const int*)d_in[5]};
  const float* ea[3] = {(const float*)d_in[2], (const float*)d_in[4], (const float*)d_in[6]};
  const float* Wp  = (const float*)d_in[7];
  const float* bp  = (const float*)d_in[8];
  const float* gp  = (const float*)d_in[9];
  const float* bep = (const float*)d_in[10];
  auto in = [&](int i) { return (const float*)d_in[i]; };
  // per-layer base 11 + 11*i: Wl, bl, Wr, br, We, att, bc, g, be, Wsk, bsk

  const int ic[3] = {64, 256, 256}, hc[3] = {256, 256, 64}, oc[3] = {256, 256, 64};

  // ---- workspace layout (~66 MB) ----
  char* w = (char*)d_ws;
  size_t off = 0;
  auto alloc = [&](size_t bytes) { void* p = w + off; off = (off + bytes + 511) & ~(size_t)511; return p; };
  ushort* B1   = (ushort*)alloc((size_t)NV * 256 * 2);  // xl (bf16)
  ushort* B2   = (ushort*)alloc((size_t)NV * 256 * 2);  // xr (bf16)
  float*  B3   = (float*)alloc((size_t)NV * 256 * 4);   // res (f32)
  ushort* h0bf = (ushort*)alloc((size_t)NV * 64 * 2);
  ushort* h1bf = (ushort*)alloc((size_t)NV * 256 * 2);
  ushort* h2bf = (ushort*)alloc((size_t)NV * 256 * 2);
  ushort* Wcat[3];
  for (int i = 0; i < 3; ++i)
    Wcat[i] = (ushort*)alloc((size_t)(2 * hc[i] + oc[i]) * ic[i] * 2);
  float* easum  = (float*)alloc(64);
  int*   counts = (int*)alloc((size_t)(NV + 1) * 4);
  int*   cursor = (int*)alloc((size_t)NV * 4);
  uint2* csr2   = (uint2*)alloc((size_t)(NE + NV) * 8);

  // ---- weight transpose-casts into concat layout [Wl | Wr | Wsk] (one launch) ----
  CJobs jobs;
  for (int i = 0; i < 3; ++i) {
    jobs.j[i * 3 + 0] = {in(11 + 11 * i), Wcat[i],                          ic[i], hc[i]};
    jobs.j[i * 3 + 1] = {in(13 + 11 * i), Wcat[i] + (size_t)hc[i] * ic[i],  ic[i], hc[i]};
    jobs.j[i * 3 + 2] = {in(20 + 11 * i), Wcat[i] + (size_t)2 * hc[i] * ic[i], ic[i], oc[i]};
  }
  cast_w_kernel<<<dim3(16, 9), 256, 0, stream>>>(jobs);

  // ---- input projection -> h0bf [N,64] ----
  proj_kernel<<<(NV + 3) / 4, 256, 0, stream>>>(x, Wp, bp, gp, bep, h0bf, NV);

  const ushort* hin[3] = {h0bf, h1bf, h2bf};
  ushort* hout_bf[3] = {h1bf, h2bf, nullptr};
  for (int i = 0; i < 3; ++i) {
    int K = ic[i], HCm = hc[i], OC = oc[i];
    int Mtot = 2 * HCm + OC;
    gemm_fused<<<dim3(Mtot / 64, (NV + 127) / 128), 256, 0, stream>>>(
        hin[i], Wcat[i], in(12 + 11 * i), in(14 + 11 * i), in(21 + 11 * i),
        B1, B2, B3, NV, K, HCm, 2 * HCm, Mtot);
    hipMemsetAsync(easum, 0, 512 + (size_t)(NV + 1) * 4, stream);
    colsum_kernel<<<64, 256, 0, stream>>>(ea[i], easum, NE);
    hist_kernel<<<(NE + NV + 255) / 256, 256, 0, stream>>>(ei[i], counts, NE, NE + NV);
    scan_kernel<<<1, 1024, 0, stream>>>(counts, cursor, NV);
    scatter_kernel<<<(NE + NV + 255) / 256, 256, 0, stream>>>(ei[i], cursor, csr2, NE, NE + NV);
    if (i < 2) {
      fused_agg_kernel<4><<<NV, 256, 0, stream>>>(
          ea[i], easum, in(15 + 11 * i), B1, B2, in(16 + 11 * i),
          in(17 + 11 * i), in(18 + 11 * i), in(19 + 11 * i), B3,
          counts, csr2, nullptr, hout_bf[i], NE);
    } else {
      fused_agg_kernel<1><<<(NV + 3) / 4, 256, 0, stream>>>(
          ea[i], easum, in(15 + 11 * i), B1, B2, in(16 + 11 * i),
          in(17 + 11 * i), in(18 + 11 * i), in(19 + 11 * i), B3,
          counts, csr2, (float*)d_out, nullptr, NE);
    }
  }
}

// Round 6
// 826.771 us; speedup vs baseline: 1.8302x; 1.2719x over previous
//
#include <hip/hip_runtime.h>
#include <hip/hip_bf16.h>
#include <math.h>

#define NV 20000
#define NE 320000
#define CSR_PAD 8

typedef __attribute__((ext_vector_type(8))) short bf16x8;
typedef __attribute__((ext_vector_type(4))) float f32x4;

static __device__ __forceinline__ ushort f2b(float f) {
  __hip_bfloat16 h = __float2bfloat16(f);
  return *reinterpret_cast<ushort*>(&h);
}
static __device__ __forceinline__ float b2f(ushort u) {
  union { ushort s[2]; float f; } c;
  c.s[0] = 0; c.s[1] = u;
  return c.f;
}

// DPP wave-64 sum: 6 VALU adds; lane 63 holds total, broadcast via readlane.
static __device__ __forceinline__ float wave_sum64(float x) {
  x += __int_as_float(__builtin_amdgcn_update_dpp(0, __float_as_int(x), 0x111, 0xF, 0xF, true));
  x += __int_as_float(__builtin_amdgcn_update_dpp(0, __float_as_int(x), 0x112, 0xF, 0xF, true));
  x += __int_as_float(__builtin_amdgcn_update_dpp(0, __float_as_int(x), 0x114, 0xF, 0xF, true));
  x += __int_as_float(__builtin_amdgcn_update_dpp(0, __float_as_int(x), 0x118, 0xF, 0xF, true));
  x += __int_as_float(__builtin_amdgcn_update_dpp(0, __float_as_int(x), 0x142, 0xA, 0xF, true));
  x += __int_as_float(__builtin_amdgcn_update_dpp(0, __float_as_int(x), 0x143, 0xC, 0xF, true));
  return __int_as_float(__builtin_amdgcn_readlane(__float_as_int(x), 63));
}

static __device__ __forceinline__ float dot16(const float4* __restrict__ p,
                                              const float* __restrict__ Wc) {
  float4 a0 = p[0], a1 = p[1], a2 = p[2], a3 = p[3];
  float s = a0.x * Wc[0];
  s = fmaf(a0.y, Wc[1], s);  s = fmaf(a0.z, Wc[2], s);  s = fmaf(a0.w, Wc[3], s);
  s = fmaf(a1.x, Wc[4], s);  s = fmaf(a1.y, Wc[5], s);  s = fmaf(a1.z, Wc[6], s);
  s = fmaf(a1.w, Wc[7], s);  s = fmaf(a2.x, Wc[8], s);  s = fmaf(a2.y, Wc[9], s);
  s = fmaf(a2.z, Wc[10], s); s = fmaf(a2.w, Wc[11], s); s = fmaf(a3.x, Wc[12], s);
  s = fmaf(a3.y, Wc[13], s); s = fmaf(a3.z, Wc[14], s); s = fmaf(a3.w, Wc[15], s);
  return s;
}

// ---------------- batched prep: CSR hist + ea colsum (y<3), W casts (y==3), proj (y==4) ----------------
struct CJob { const float* src; ushort* dst; int K, M; };
struct PrepArgs {
  const int* ei[3];
  const float* ea[3];
  int* counts[3];
  float* easum[3];
  CJob jobs[9];
  const float *x, *Wp, *bp, *gp, *bep;
  ushort* h0;
};

__global__ __launch_bounds__(256) void prep_kernel(PrepArgs a) {
  const int y = blockIdx.y, t = threadIdx.x;
  if (y < 3) {
    // --- ea column sums (grid-stride) ---
    const float* ea = a.ea[y];
    {
      int col = t & 15;
      int r = blockIdx.x * 16 + (t >> 4);
      int rstride = gridDim.x * 16;
      float s = 0.0f;
      for (; r < NE; r += rstride) s += ea[(size_t)r * 16 + col];
      __shared__ float red[256];
      red[t] = s;
      __syncthreads();
      if (t < 16) {
        float tot = 0.0f;
        for (int j = t; j < 256; j += 16) tot += red[j];
        atomicAdd(&a.easum[y][t], tot);
      }
    }
    // --- dst histogram (incl. self loops) ---
    int i = blockIdx.x * 256 + t;
    if (i < NE + NV) {
      int dst = (i < NE) ? a.ei[y][NE + i] : (i - NE);
      atomicAdd(&a.counts[y][dst], 1);
    }
  } else if (y == 3) {
    // --- weight transpose-casts ---
#pragma unroll
    for (int j = 0; j < 9; ++j) {
      CJob jb = a.jobs[j];
      const int total = jb.M * jb.K;
      for (int i = blockIdx.x * 256 + t; i < total; i += gridDim.x * 256) {
        int m = i / jb.K, k = i - m * jb.K;
        jb.dst[i] = f2b(jb.src[(size_t)k * jb.M + m]);
      }
    }
  } else {
    // --- proj: h0 = gelu(LN(x@Wp + bp)) ---
    int wid = t >> 6, lane = t & 63;
    int row = blockIdx.x * 4 + wid;
    if (row >= NV) return;
    float xv = a.x[(size_t)row * 64 + lane];
    float acc = a.bp[lane];
#pragma unroll
    for (int k = 0; k < 64; ++k) {
      float v = __shfl(xv, k, 64);
      acc = fmaf(v, a.Wp[k * 64 + lane], acc);
    }
    float s1 = wave_sum64(acc), s2 = wave_sum64(acc * acc);
    float mean = s1 * (1.0f / 64.0f);
    float var  = s2 * (1.0f / 64.0f) - mean * mean;
    float yv = (acc - mean) * rsqrtf(var + 1e-5f) * a.gp[lane] + a.bep[lane];
    float gel = 0.5f * yv * (1.0f + erff(yv * 0.70710678118654752f));
    a.h0[(size_t)row * 64 + lane] = f2b(gel);
  }
}

// ---------------- batched scan: blockIdx.x = layer ----------------
__global__ __launch_bounds__(1024) void scan_kernel(
    int* __restrict__ countsA, int* __restrict__ cursorA)
{
  int* counts = countsA + blockIdx.x * (NV + 1);
  int* cursor = cursorA + blockIdx.x * NV;
  __shared__ int ws[16];
  __shared__ int wexcl[17];
  const int t = threadIdx.x, lane = t & 63, wid = t >> 6;
  const int base = t * 20;
  int v[20];
  int tot = 0;
#pragma unroll
  for (int j = 0; j < 20; ++j) {
    int i = base + j;
    v[j] = (i < NV) ? counts[i] : 0;
    tot += v[j];
  }
  int x = tot;
#pragma unroll
  for (int o = 1; o < 64; o <<= 1) {
    int yy = __shfl_up(x, o, 64);
    if (lane >= o) x += yy;
  }
  if (lane == 63) ws[wid] = x;
  __syncthreads();
  if (t == 0) {
    int r = 0;
#pragma unroll
    for (int j = 0; j < 16; ++j) { wexcl[j] = r; r += ws[j]; }
    wexcl[16] = r;
  }
  __syncthreads();
  int run = wexcl[wid] + (x - tot);
#pragma unroll
  for (int j = 0; j < 20; ++j) {
    int i = base + j;
    if (i < NV) { counts[i] = run; cursor[i] = run; }
    run += v[j];
  }
  if (t == 0) counts[NV] = wexcl[16];
}

// ---------------- batched scatter: (src, edge_id) pairs; blockIdx.y = layer ----------------
struct ScatArgs { const int* ei[3]; int* cursor[3]; uint2* csr2[3]; };
__global__ __launch_bounds__(256) void scatter_kernel(ScatArgs a) {
  const int l = blockIdx.y;
  const int total = NE + NV;
  int i = blockIdx.x * 256 + threadIdx.x;
  if (i >= total + CSR_PAD) return;
  if (i >= total) { a.csr2[l][i] = make_uint2(0u, 0u); return; }  // prefetch pad
  int dst, src;
  if (i < NE) { dst = a.ei[l][NE + i]; src = a.ei[l][i]; }
  else        { dst = i - NE;          src = i - NE; }
  int pos = atomicAdd(&a.cursor[l][dst], 1);
  a.csr2[l][pos] = make_uint2((unsigned)src, (unsigned)i);
}

// ---------------- fused per-layer GEMM: [xl | xr | res] = A @ [Wl|Wr|Wsk] + bias ----------------
__global__ __launch_bounds__(256) void gemm_fused(
    const ushort* __restrict__ A, const ushort* __restrict__ WT,
    const float* __restrict__ b0, const float* __restrict__ b1,
    const float* __restrict__ b2,
    ushort* __restrict__ O0, ushort* __restrict__ O1, float* __restrict__ O2,
    int N, int K, int M1, int M2, int Mtot)
{
  __shared__ ushort As[128][40];
  __shared__ ushort Bs[64][40];
  const int t = threadIdx.x, wave = t >> 6, lane = t & 63;
  const int row0 = blockIdx.y * 128, col0 = blockIdx.x * 64;
  const int m_ = lane & 15, q = lane >> 4;
  f32x4 acc[2][4];
#pragma unroll
  for (int i = 0; i < 2; ++i)
#pragma unroll
    for (int j = 0; j < 4; ++j) acc[i][j] = (f32x4){0.f, 0.f, 0.f, 0.f};

  const int ar = t >> 1, ac = (t & 1) * 16;
  const int br = t >> 2, bcol = (t & 3) * 8;
  const ushort* Ap = A + (size_t)(row0 + ar) * K + ac;
  const ushort* Bp = WT + (size_t)(col0 + br) * K + bcol;
  const bool a_ok = (row0 + ar) < N;

  for (int k0 = 0; k0 < K; k0 += 32) {
    uint4 av0 = make_uint4(0, 0, 0, 0), av1 = make_uint4(0, 0, 0, 0);
    if (a_ok) { av0 = *(const uint4*)(Ap + k0); av1 = *(const uint4*)(Ap + k0 + 8); }
    uint4 bv = *(const uint4*)(Bp + k0);
    *(uint4*)&As[ar][ac] = av0;
    *(uint4*)&As[ar][ac + 8] = av1;
    *(uint4*)&Bs[br][bcol] = bv;
    __syncthreads();
    bf16x8 a0 = *(const bf16x8*)&As[wave * 32 + m_][q * 8];
    bf16x8 a1 = *(const bf16x8*)&As[wave * 32 + 16 + m_][q * 8];
#pragma unroll
    for (int cf = 0; cf < 4; ++cf) {
      bf16x8 b = *(const bf16x8*)&Bs[cf * 16 + m_][q * 8];
      acc[0][cf] = __builtin_amdgcn_mfma_f32_16x16x32_bf16(a0, b, acc[0][cf], 0, 0, 0);
      acc[1][cf] = __builtin_amdgcn_mfma_f32_16x16x32_bf16(a1, b, acc[1][cf], 0, 0, 0);
    }
    __syncthreads();
  }

  const float* bias; int base, mode, Wd;
  if (col0 < M1)      { bias = b0; base = 0;  mode = 0; Wd = M1; }
  else if (col0 < M2) { bias = b1; base = M1; mode = 1; Wd = M2 - M1; }
  else                { bias = b2; base = M2; mode = 2; Wd = Mtot - M2; }

#pragma unroll
  for (int rf = 0; rf < 2; ++rf) {
#pragma unroll
    for (int cf = 0; cf < 4; ++cf) {
      int col = col0 + cf * 16 + m_ - base;
      float bb = bias[col];
#pragma unroll
      for (int r = 0; r < 4; ++r) {
        int row = row0 + wave * 32 + rf * 16 + q * 4 + r;
        if (row < N) {
          float v = acc[rf][cf][r] + bb;
          if (mode == 0)      O0[(size_t)row * Wd + col] = f2b(v);
          else if (mode == 1) O1[(size_t)row * Wd + col] = f2b(v);
          else                O2[(size_t)row * Wd + col] = v;
        }
      }
    }
  }
}

// ---------------- fused GATv2: score + softmax + aggregate + LN + gelu + res ----------------
// H=4: one block (4 waves) per node. H=1: one wave per node, 4 nodes/block.
// 4-edge ILP; csr2 padded by CSR_PAD so prefetch needs no clamping.
template <int H>
__global__ __launch_bounds__(256, 4) void fused_agg_kernel(
    const float* __restrict__ ea, const float* __restrict__ easum,
    const float* __restrict__ We,
    const ushort* __restrict__ xl, const ushort* __restrict__ xr,
    const float* __restrict__ att, const float* __restrict__ bc,
    const float* __restrict__ g, const float* __restrict__ be,
    const float* __restrict__ res,
    const int* __restrict__ offs, const uint2* __restrict__ csr2,
    float* __restrict__ houtf, ushort* __restrict__ houtb, int E)
{
  const int HC = H * 64;
  const int t = threadIdx.x, lane = t & 63, wave = t >> 6;
  const int n = (H == 1) ? blockIdx.x * 4 + wave : blockIdx.x;
  const int c = (H == 1) ? lane : t;

  const float xr_t = b2f(xr[(size_t)n * HC + c]);
  const float att_t = att[c];
  float Wc[16];
#pragma unroll
  for (int k = 0; k < 16; ++k) Wc[k] = We[k * HC + c];
  float eself = 0.f;
#pragma unroll
  for (int k = 0; k < 16; ++k) eself = fmaf(easum[k], Wc[k], eself);
  eself *= 1.0f / (float)E;

  float acc = 0.f, denom = 0.f;
  const int beg = offs[n], end = offs[n + 1];

  uint2 P[4];
#pragma unroll
  for (int k = 0; k < 4; ++k) P[k] = csr2[beg + k];

  for (int idx = beg; idx < end; idx += 4) {
    uint2 Q[4];
#pragma unroll
    for (int k = 0; k < 4; ++k) Q[k] = csr2[idx + 4 + k];

    float xls[4], ee[4], wv[4];
#pragma unroll
    for (int k = 0; k < 4; ++k) {
      const int e = (int)P[k].y, src = (int)P[k].x;
      const float4* p = (const float4*)(ea + (size_t)min(e, E - 1) * 16);
      ee[k] = dot16(p, Wc);
      if (e >= E) ee[k] = eself;
      xls[k] = b2f(xl[(size_t)src * HC + c]);
    }
#pragma unroll
    for (int k = 0; k < 4; ++k) {
      float v = xls[k] + xr_t + ee[k];
      v = v > 0.f ? v : 0.2f * v;  // leaky_relu(0.2)
      float S = wave_sum64(v * att_t);
      wv[k] = (idx + k < end) ? __expf(S) : 0.f;
    }
#pragma unroll
    for (int k = 0; k < 4; ++k) { acc = fmaf(wv[k], xls[k], acc); denom += wv[k]; }
#pragma unroll
    for (int k = 0; k < 4; ++k) P[k] = Q[k];
  }

  float out = acc / (denom + 1e-16f) + bc[c];

  // LayerNorm across HC channels
  float s1 = wave_sum64(out), s2 = wave_sum64(out * out);
  if (H > 1) {
    __shared__ float r1s[4], r2s[4];
    if (lane == 0) { r1s[wave] = s1; r2s[wave] = s2; }
    __syncthreads();
    s1 = 0.f; s2 = 0.f;
#pragma unroll
    for (int j = 0; j < H; ++j) { s1 += r1s[j]; s2 += r2s[j]; }
  }
  float mean = s1 / (float)HC;
  float var  = s2 / (float)HC - mean * mean;
  float y = (out - mean) * rsqrtf(var + 1e-5f) * g[c] + be[c];
  float gel = 0.5f * y * (1.0f + erff(y * 0.70710678118654752f));
  float o = gel + res[(size_t)n * HC + c];
  if (houtf) houtf[(size_t)n * HC + c] = o;
  if (houtb) houtb[(size_t)n * HC + c] = f2b(o);
}

// ---------------- host launch ----------------
extern "C" void kernel_launch(void* const* d_in, const int* in_sizes, int n_in,
                              void* d_out, int out_size, void* d_ws, size_t ws_size,
                              hipStream_t stream)
{
  const float* x = (const float*)d_in[0];
  const int*   ei[3] = {(const int*)d_in[1], (const int*)d_in[3], (const int*)d_in[5]};
  const float* ea[3] = {(const float*)d_in[2], (const float*)d_in[4], (const float*)d_in[6]};
  auto in = [&](int i) { return (const float*)d_in[i]; };
  // per-layer base 11 + 11*i: Wl, bl, Wr, br, We, att, bc, g, be, Wsk, bsk

  const int ic[3] = {64, 256, 256}, hc[3] = {256, 256, 64}, oc[3] = {256, 256, 64};
  const int CSRN = NE + NV + CSR_PAD;

  // ---- workspace layout (~76 MB) ----
  char* w = (char*)d_ws;
  size_t off = 0;
  auto alloc = [&](size_t bytes) { void* p = w + off; off = (off + bytes + 511) & ~(size_t)511; return p; };
  ushort* B1   = (ushort*)alloc((size_t)NV * 256 * 2);  // xl (bf16)
  ushort* B2   = (ushort*)alloc((size_t)NV * 256 * 2);  // xr (bf16)
  float*  B3   = (float*)alloc((size_t)NV * 256 * 4);   // res (f32)
  ushort* h0bf = (ushort*)alloc((size_t)NV * 64 * 2);
  ushort* h1bf = (ushort*)alloc((size_t)NV * 256 * 2);
  ushort* h2bf = (ushort*)alloc((size_t)NV * 256 * 2);
  ushort* Wcat[3];
  for (int i = 0; i < 3; ++i)
    Wcat[i] = (ushort*)alloc((size_t)(2 * hc[i] + oc[i]) * ic[i] * 2);
  float* easumA  = (float*)alloc(3 * 64);                    // 3 x 16 floats
  int*   countsA = (int*)alloc((size_t)3 * (NV + 1) * 4);    // adjacent to easumA for one memset
  int*   cursorA = (int*)alloc((size_t)3 * NV * 4);
  uint2* csr2A   = (uint2*)alloc((size_t)3 * CSRN * 8);

  // ---- single memset: easums + counts ----
  hipMemsetAsync(easumA, 0, 512 + (size_t)3 * (NV + 1) * 4, stream);

  // ---- batched prep: CSR hist + colsum (x3), weight casts, proj ----
  PrepArgs pa;
  for (int i = 0; i < 3; ++i) {
    pa.ei[i] = ei[i];
    pa.ea[i] = ea[i];
    pa.counts[i] = countsA + i * (NV + 1);
    pa.easum[i] = easumA + i * 16;
    pa.jobs[i * 3 + 0] = {in(11 + 11 * i), Wcat[i],                             ic[i], hc[i]};
    pa.jobs[i * 3 + 1] = {in(13 + 11 * i), Wcat[i] + (size_t)hc[i] * ic[i],     ic[i], hc[i]};
    pa.jobs[i * 3 + 2] = {in(20 + 11 * i), Wcat[i] + (size_t)2 * hc[i] * ic[i], ic[i], oc[i]};
  }
  pa.x = x; pa.Wp = in(7); pa.bp = in(8); pa.gp = in(9); pa.bep = in(10); pa.h0 = h0bf;
  prep_kernel<<<dim3(5000, 5), 256, 0, stream>>>(pa);

  // ---- batched scan + scatter ----
  scan_kernel<<<3, 1024, 0, stream>>>(countsA, cursorA);
  ScatArgs sa;
  for (int i = 0; i < 3; ++i) {
    sa.ei[i] = ei[i];
    sa.cursor[i] = cursorA + i * NV;
    sa.csr2[i] = csr2A + (size_t)i * CSRN;
  }
  scatter_kernel<<<dim3((NE + NV + CSR_PAD + 255) / 256, 3), 256, 0, stream>>>(sa);

  // ---- per-layer: fused GEMM + fused aggregate ----
  const ushort* hin[3] = {h0bf, h1bf, h2bf};
  ushort* hout_bf[3] = {h1bf, h2bf, nullptr};
  for (int i = 0; i < 3; ++i) {
    int K = ic[i], HCm = hc[i], OC = oc[i];
    int Mtot = 2 * HCm + OC;
    gemm_fused<<<dim3(Mtot / 64, (NV + 127) / 128), 256, 0, stream>>>(
        hin[i], Wcat[i], in(12 + 11 * i), in(14 + 11 * i), in(21 + 11 * i),
        B1, B2, B3, NV, K, HCm, 2 * HCm, Mtot);
    const int* offs = countsA + i * (NV + 1);
    const uint2* csr2 = csr2A + (size_t)i * CSRN;
    const float* easum = easumA + i * 16;
    if (i < 2) {
      fused_agg_kernel<4><<<NV, 256, 0, stream>>>(
          ea[i], easum, in(15 + 11 * i), B1, B2, in(16 + 11 * i),
          in(17 + 11 * i), in(18 + 11 * i), in(19 + 11 * i), B3,
          offs, csr2, nullptr, hout_bf[i], NE);
    } else {
      fused_agg_kernel<1><<<(NV + 3) / 4, 256, 0, stream>>>(
          ea[i], easum, in(15 + 11 * i), B1, B2, in(16 + 11 * i),
          in(17 + 11 * i), in(18 + 11 * i), in(19 + 11 * i), B3,
          offs, csr2, (float*)d_out, nullptr, NE);
    }
  }
}

// Round 7
// 729.923 us; speedup vs baseline: 2.0730x; 1.1327x over previous
//
#include <hip/hip_runtime.h>
#include <hip/hip_bf16.h>
#include <math.h>

#define NV 20000
#define NE 320000
#define CSR_PAD 8

typedef __attribute__((ext_vector_type(8))) short bf16x8;
typedef __attribute__((ext_vector_type(4))) float f32x4;

static __device__ __forceinline__ ushort f2b(float f) {
  __hip_bfloat16 h = __float2bfloat16(f);
  return *reinterpret_cast<ushort*>(&h);
}
static __device__ __forceinline__ float b2f(ushort u) {
  union { ushort s[2]; float f; } c;
  c.s[0] = 0; c.s[1] = u;
  return c.f;
}

// DPP wave-64 sum: 6 VALU adds; lane 63 holds total, broadcast via readlane.
static __device__ __forceinline__ float wave_sum64(float x) {
  x += __int_as_float(__builtin_amdgcn_update_dpp(0, __float_as_int(x), 0x111, 0xF, 0xF, true));
  x += __int_as_float(__builtin_amdgcn_update_dpp(0, __float_as_int(x), 0x112, 0xF, 0xF, true));
  x += __int_as_float(__builtin_amdgcn_update_dpp(0, __float_as_int(x), 0x114, 0xF, 0xF, true));
  x += __int_as_float(__builtin_amdgcn_update_dpp(0, __float_as_int(x), 0x118, 0xF, 0xF, true));
  x += __int_as_float(__builtin_amdgcn_update_dpp(0, __float_as_int(x), 0x142, 0xA, 0xF, true));
  x += __int_as_float(__builtin_amdgcn_update_dpp(0, __float_as_int(x), 0x143, 0xC, 0xF, true));
  return __int_as_float(__builtin_amdgcn_readlane(__float_as_int(x), 63));
}

static __device__ __forceinline__ float dot16(const float4* __restrict__ p,
                                              const float* __restrict__ Wc) {
  float4 a0 = p[0], a1 = p[1], a2 = p[2], a3 = p[3];
  float s = a0.x * Wc[0];
  s = fmaf(a0.y, Wc[1], s);  s = fmaf(a0.z, Wc[2], s);  s = fmaf(a0.w, Wc[3], s);
  s = fmaf(a1.x, Wc[4], s);  s = fmaf(a1.y, Wc[5], s);  s = fmaf(a1.z, Wc[6], s);
  s = fmaf(a1.w, Wc[7], s);  s = fmaf(a2.x, Wc[8], s);  s = fmaf(a2.y, Wc[9], s);
  s = fmaf(a2.z, Wc[10], s); s = fmaf(a2.w, Wc[11], s); s = fmaf(a3.x, Wc[12], s);
  s = fmaf(a3.y, Wc[13], s); s = fmaf(a3.z, Wc[14], s); s = fmaf(a3.w, Wc[15], s);
  return s;
}

// ---------------- batched prep: CSR hist + ea colsum (y<3), W casts (y==3), proj (y==4) ----------------
struct CJob { const float* src; ushort* dst; int K, M; };
struct PrepArgs {
  const int* ei[3];
  const float* ea[3];
  int* counts[3];
  float* easum[3];
  CJob jobs[9];
  const float *x, *Wp, *bp, *gp, *bep;
  ushort* h0;
};

__global__ __launch_bounds__(256) void prep_kernel(PrepArgs a) {
  const int y = blockIdx.y, t = threadIdx.x;
  if (y < 3) {
    // --- ea column sums: only first 256 blocks, float4 loads, ONE shared
    //     reduction -> 16 atomics/block (round-6's 80k same-line atomics
    //     from 5000 blocks serialized at L2 and dominated the kernel) ---
    if (blockIdx.x < 256) {
      const float4* ea4 = (const float4*)a.ea[y];
      const int cg = t & 3;                 // which float4 of the 16-col row
      int r = blockIdx.x * 64 + (t >> 2);
      const int rstride = 256 * 64;
      float4 s = make_float4(0.f, 0.f, 0.f, 0.f);
      for (; r < NE; r += rstride) {
        float4 v = ea4[(size_t)r * 4 + cg];
        s.x += v.x; s.y += v.y; s.z += v.z; s.w += v.w;
      }
      __shared__ float4 red4[256];
      red4[t] = s;
      __syncthreads();
      if (t < 4) {
        float4 tot = make_float4(0.f, 0.f, 0.f, 0.f);
        for (int j = t; j < 256; j += 4) {
          float4 v = red4[j];
          tot.x += v.x; tot.y += v.y; tot.z += v.z; tot.w += v.w;
        }
        atomicAdd(&a.easum[y][t * 4 + 0], tot.x);
        atomicAdd(&a.easum[y][t * 4 + 1], tot.y);
        atomicAdd(&a.easum[y][t * 4 + 2], tot.z);
        atomicAdd(&a.easum[y][t * 4 + 3], tot.w);
      }
    }
    // --- dst histogram (incl. self loops) ---
    int i = blockIdx.x * 256 + t;
    if (i < NE + NV) {
      int dst = (i < NE) ? a.ei[y][NE + i] : (i - NE);
      atomicAdd(&a.counts[y][dst], 1);
    }
  } else if (y == 3) {
    // --- weight transpose-casts ---
#pragma unroll
    for (int j = 0; j < 9; ++j) {
      CJob jb = a.jobs[j];
      const int total = jb.M * jb.K;
      for (int i = blockIdx.x * 256 + t; i < total; i += gridDim.x * 256) {
        int m = i / jb.K, k = i - m * jb.K;
        jb.dst[i] = f2b(jb.src[(size_t)k * jb.M + m]);
      }
    }
  } else {
    // --- proj: h0 = gelu(LN(x@Wp + bp)) (grid-stride over rows) ---
    int wid = t >> 6, lane = t & 63;
    for (int row = blockIdx.x * 4 + wid; row < NV; row += gridDim.x * 4) {
      float xv = a.x[(size_t)row * 64 + lane];
      float acc = a.bp[lane];
#pragma unroll
      for (int k = 0; k < 64; ++k) {
        float v = __shfl(xv, k, 64);
        acc = fmaf(v, a.Wp[k * 64 + lane], acc);
      }
      float s1 = wave_sum64(acc), s2 = wave_sum64(acc * acc);
      float mean = s1 * (1.0f / 64.0f);
      float var  = s2 * (1.0f / 64.0f) - mean * mean;
      float yv = (acc - mean) * rsqrtf(var + 1e-5f) * a.gp[lane] + a.bep[lane];
      float gel = 0.5f * yv * (1.0f + erff(yv * 0.70710678118654752f));
      a.h0[(size_t)row * 64 + lane] = f2b(gel);
    }
  }
}

// ---------------- batched scan: blockIdx.x = layer ----------------
__global__ __launch_bounds__(1024) void scan_kernel(
    int* __restrict__ countsA, int* __restrict__ cursorA)
{
  int* counts = countsA + blockIdx.x * (NV + 1);
  int* cursor = cursorA + blockIdx.x * NV;
  __shared__ int ws[16];
  __shared__ int wexcl[17];
  const int t = threadIdx.x, lane = t & 63, wid = t >> 6;
  const int base = t * 20;
  int v[20];
  int tot = 0;
#pragma unroll
  for (int j = 0; j < 20; ++j) {
    int i = base + j;
    v[j] = (i < NV) ? counts[i] : 0;
    tot += v[j];
  }
  int x = tot;
#pragma unroll
  for (int o = 1; o < 64; o <<= 1) {
    int yy = __shfl_up(x, o, 64);
    if (lane >= o) x += yy;
  }
  if (lane == 63) ws[wid] = x;
  __syncthreads();
  if (t == 0) {
    int r = 0;
#pragma unroll
    for (int j = 0; j < 16; ++j) { wexcl[j] = r; r += ws[j]; }
    wexcl[16] = r;
  }
  __syncthreads();
  int run = wexcl[wid] + (x - tot);
#pragma unroll
  for (int j = 0; j < 20; ++j) {
    int i = base + j;
    if (i < NV) { counts[i] = run; cursor[i] = run; }
    run += v[j];
  }
  if (t == 0) counts[NV] = wexcl[16];
}

// ---------------- batched scatter: (src, edge_id) pairs; blockIdx.y = layer ----------------
struct ScatArgs { const int* ei[3]; int* cursor[3]; uint2* csr2[3]; };
__global__ __launch_bounds__(256) void scatter_kernel(ScatArgs a) {
  const int l = blockIdx.y;
  const int total = NE + NV;
  int i = blockIdx.x * 256 + threadIdx.x;
  if (i >= total + CSR_PAD) return;
  if (i >= total) { a.csr2[l][i] = make_uint2(0u, 0u); return; }  // prefetch pad
  int dst, src;
  if (i < NE) { dst = a.ei[l][NE + i]; src = a.ei[l][i]; }
  else        { dst = i - NE;          src = i - NE; }
  int pos = atomicAdd(&a.cursor[l][dst], 1);
  a.csr2[l][pos] = make_uint2((unsigned)src, (unsigned)i);
}

// ---------------- fused per-layer GEMM: [xl | xr | res] = A @ [Wl|Wr|Wsk] + bias ----------------
__global__ __launch_bounds__(256) void gemm_fused(
    const ushort* __restrict__ A, const ushort* __restrict__ WT,
    const float* __restrict__ b0, const float* __restrict__ b1,
    const float* __restrict__ b2,
    ushort* __restrict__ O0, ushort* __restrict__ O1, float* __restrict__ O2,
    int N, int K, int M1, int M2, int Mtot)
{
  __shared__ ushort As[128][40];
  __shared__ ushort Bs[64][40];
  const int t = threadIdx.x, wave = t >> 6, lane = t & 63;
  const int row0 = blockIdx.y * 128, col0 = blockIdx.x * 64;
  const int m_ = lane & 15, q = lane >> 4;
  f32x4 acc[2][4];
#pragma unroll
  for (int i = 0; i < 2; ++i)
#pragma unroll
    for (int j = 0; j < 4; ++j) acc[i][j] = (f32x4){0.f, 0.f, 0.f, 0.f};

  const int ar = t >> 1, ac = (t & 1) * 16;
  const int br = t >> 2, bcol = (t & 3) * 8;
  const ushort* Ap = A + (size_t)(row0 + ar) * K + ac;
  const ushort* Bp = WT + (size_t)(col0 + br) * K + bcol;
  const bool a_ok = (row0 + ar) < N;

  for (int k0 = 0; k0 < K; k0 += 32) {
    uint4 av0 = make_uint4(0, 0, 0, 0), av1 = make_uint4(0, 0, 0, 0);
    if (a_ok) { av0 = *(const uint4*)(Ap + k0); av1 = *(const uint4*)(Ap + k0 + 8); }
    uint4 bv = *(const uint4*)(Bp + k0);
    *(uint4*)&As[ar][ac] = av0;
    *(uint4*)&As[ar][ac + 8] = av1;
    *(uint4*)&Bs[br][bcol] = bv;
    __syncthreads();
    bf16x8 a0 = *(const bf16x8*)&As[wave * 32 + m_][q * 8];
    bf16x8 a1 = *(const bf16x8*)&As[wave * 32 + 16 + m_][q * 8];
#pragma unroll
    for (int cf = 0; cf < 4; ++cf) {
      bf16x8 b = *(const bf16x8*)&Bs[cf * 16 + m_][q * 8];
      acc[0][cf] = __builtin_amdgcn_mfma_f32_16x16x32_bf16(a0, b, acc[0][cf], 0, 0, 0);
      acc[1][cf] = __builtin_amdgcn_mfma_f32_16x16x32_bf16(a1, b, acc[1][cf], 0, 0, 0);
    }
    __syncthreads();
  }

  const float* bias; int base, mode, Wd;
  if (col0 < M1)      { bias = b0; base = 0;  mode = 0; Wd = M1; }
  else if (col0 < M2) { bias = b1; base = M1; mode = 1; Wd = M2 - M1; }
  else                { bias = b2; base = M2; mode = 2; Wd = Mtot - M2; }

#pragma unroll
  for (int rf = 0; rf < 2; ++rf) {
#pragma unroll
    for (int cf = 0; cf < 4; ++cf) {
      int col = col0 + cf * 16 + m_ - base;
      float bb = bias[col];
#pragma unroll
      for (int r = 0; r < 4; ++r) {
        int row = row0 + wave * 32 + rf * 16 + q * 4 + r;
        if (row < N) {
          float v = acc[rf][cf][r] + bb;
          if (mode == 0)      O0[(size_t)row * Wd + col] = f2b(v);
          else if (mode == 1) O1[(size_t)row * Wd + col] = f2b(v);
          else                O2[(size_t)row * Wd + col] = v;
        }
      }
    }
  }
}

// ---------------- fused GATv2: score + softmax + aggregate + LN + gelu + res ----------------
// H=4: one block (4 waves) per node. H=1: one wave per node, 4 nodes/block.
// 4-edge ILP; csr2 padded by CSR_PAD so prefetch needs no clamping.
template <int H>
__global__ __launch_bounds__(256, 4) void fused_agg_kernel(
    const float* __restrict__ ea, const float* __restrict__ easum,
    const float* __restrict__ We,
    const ushort* __restrict__ xl, const ushort* __restrict__ xr,
    const float* __restrict__ att, const float* __restrict__ bc,
    const float* __restrict__ g, const float* __restrict__ be,
    const float* __restrict__ res,
    const int* __restrict__ offs, const uint2* __restrict__ csr2,
    float* __restrict__ houtf, ushort* __restrict__ houtb, int E)
{
  const int HC = H * 64;
  const int t = threadIdx.x, lane = t & 63, wave = t >> 6;
  const int n = (H == 1) ? blockIdx.x * 4 + wave : blockIdx.x;
  const int c = (H == 1) ? lane : t;

  const float xr_t = b2f(xr[(size_t)n * HC + c]);
  const float att_t = att[c];
  float Wc[16];
#pragma unroll
  for (int k = 0; k < 16; ++k) Wc[k] = We[k * HC + c];
  float eself = 0.f;
#pragma unroll
  for (int k = 0; k < 16; ++k) eself = fmaf(easum[k], Wc[k], eself);
  eself *= 1.0f / (float)E;

  float acc = 0.f, denom = 0.f;
  const int beg = offs[n], end = offs[n + 1];

  uint2 P[4];
#pragma unroll
  for (int k = 0; k < 4; ++k) P[k] = csr2[beg + k];

  for (int idx = beg; idx < end; idx += 4) {
    uint2 Q[4];
#pragma unroll
    for (int k = 0; k < 4; ++k) Q[k] = csr2[idx + 4 + k];

    float xls[4], ee[4], wv[4];
#pragma unroll
    for (int k = 0; k < 4; ++k) {
      const int e = (int)P[k].y, src = (int)P[k].x;
      const float4* p = (const float4*)(ea + (size_t)min(e, E - 1) * 16);
      ee[k] = dot16(p, Wc);
      if (e >= E) ee[k] = eself;
      xls[k] = b2f(xl[(size_t)src * HC + c]);
    }
#pragma unroll
    for (int k = 0; k < 4; ++k) {
      float v = xls[k] + xr_t + ee[k];
      v = v > 0.f ? v : 0.2f * v;  // leaky_relu(0.2)
      float S = wave_sum64(v * att_t);
      wv[k] = (idx + k < end) ? __expf(S) : 0.f;
    }
#pragma unroll
    for (int k = 0; k < 4; ++k) { acc = fmaf(wv[k], xls[k], acc); denom += wv[k]; }
#pragma unroll
    for (int k = 0; k < 4; ++k) P[k] = Q[k];
  }

  float out = acc / (denom + 1e-16f) + bc[c];

  // LayerNorm across HC channels
  float s1 = wave_sum64(out), s2 = wave_sum64(out * out);
  if (H > 1) {
    __shared__ float r1s[4], r2s[4];
    if (lane == 0) { r1s[wave] = s1; r2s[wave] = s2; }
    __syncthreads();
    s1 = 0.f; s2 = 0.f;
#pragma unroll
    for (int j = 0; j < H; ++j) { s1 += r1s[j]; s2 += r2s[j]; }
  }
  float mean = s1 / (float)HC;
  float var  = s2 / (float)HC - mean * mean;
  float y = (out - mean) * rsqrtf(var + 1e-5f) * g[c] + be[c];
  float gel = 0.5f * y * (1.0f + erff(y * 0.70710678118654752f));
  float o = gel + res[(size_t)n * HC + c];
  if (houtf) houtf[(size_t)n * HC + c] = o;
  if (houtb) houtb[(size_t)n * HC + c] = f2b(o);
}

// ---------------- host launch ----------------
extern "C" void kernel_launch(void* const* d_in, const int* in_sizes, int n_in,
                              void* d_out, int out_size, void* d_ws, size_t ws_size,
                              hipStream_t stream)
{
  const float* x = (const float*)d_in[0];
  const int*   ei[3] = {(const int*)d_in[1], (const int*)d_in[3], (const int*)d_in[5]};
  const float* ea[3] = {(const float*)d_in[2], (const float*)d_in[4], (const float*)d_in[6]};
  auto in = [&](int i) { return (const float*)d_in[i]; };
  // per-layer base 11 + 11*i: Wl, bl, Wr, br, We, att, bc, g, be, Wsk, bsk

  const int ic[3] = {64, 256, 256}, hc[3] = {256, 256, 64}, oc[3] = {256, 256, 64};
  const int CSRN = NE + NV + CSR_PAD;

  // ---- workspace layout (~76 MB) ----
  char* w = (char*)d_ws;
  size_t off = 0;
  auto alloc = [&](size_t bytes) { void* p = w + off; off = (off + bytes + 511) & ~(size_t)511; return p; };
  ushort* B1   = (ushort*)alloc((size_t)NV * 256 * 2);  // xl (bf16)
  ushort* B2   = (ushort*)alloc((size_t)NV * 256 * 2);  // xr (bf16)
  float*  B3   = (float*)alloc((size_t)NV * 256 * 4);   // res (f32)
  ushort* h0bf = (ushort*)alloc((size_t)NV * 64 * 2);
  ushort* h1bf = (ushort*)alloc((size_t)NV * 256 * 2);
  ushort* h2bf = (ushort*)alloc((size_t)NV * 256 * 2);
  ushort* Wcat[3];
  for (int i = 0; i < 3; ++i)
    Wcat[i] = (ushort*)alloc((size_t)(2 * hc[i] + oc[i]) * ic[i] * 2);
  float* easumA  = (float*)alloc(3 * 64);                    // 3 x 16 floats
  int*   countsA = (int*)alloc((size_t)3 * (NV + 1) * 4);    // adjacent to easumA for one memset
  int*   cursorA = (int*)alloc((size_t)3 * NV * 4);
  uint2* csr2A   = (uint2*)alloc((size_t)3 * CSRN * 8);

  // ---- single memset: easums + counts ----
  hipMemsetAsync(easumA, 0, 512 + (size_t)3 * (NV + 1) * 4, stream);

  // ---- batched prep: CSR hist + colsum (x3), weight casts, proj ----
  PrepArgs pa;
  for (int i = 0; i < 3; ++i) {
    pa.ei[i] = ei[i];
    pa.ea[i] = ea[i];
    pa.counts[i] = countsA + i * (NV + 1);
    pa.easum[i] = easumA + i * 16;
    pa.jobs[i * 3 + 0] = {in(11 + 11 * i), Wcat[i],                             ic[i], hc[i]};
    pa.jobs[i * 3 + 1] = {in(13 + 11 * i), Wcat[i] + (size_t)hc[i] * ic[i],     ic[i], hc[i]};
    pa.jobs[i * 3 + 2] = {in(20 + 11 * i), Wcat[i] + (size_t)2 * hc[i] * ic[i], ic[i], oc[i]};
  }
  pa.x = x; pa.Wp = in(7); pa.bp = in(8); pa.gp = in(9); pa.bep = in(10); pa.h0 = h0bf;
  prep_kernel<<<dim3(1344, 5), 256, 0, stream>>>(pa);

  // ---- batched scan + scatter ----
  scan_kernel<<<3, 1024, 0, stream>>>(countsA, cursorA);
  ScatArgs sa;
  for (int i = 0; i < 3; ++i) {
    sa.ei[i] = ei[i];
    sa.cursor[i] = cursorA + i * NV;
    sa.csr2[i] = csr2A + (size_t)i * CSRN;
  }
  scatter_kernel<<<dim3((NE + NV + CSR_PAD + 255) / 256, 3), 256, 0, stream>>>(sa);

  // ---- per-layer: fused GEMM + fused aggregate ----
  const ushort* hin[3] = {h0bf, h1bf, h2bf};
  ushort* hout_bf[3] = {h1bf, h2bf, nullptr};
  for (int i = 0; i < 3; ++i) {
    int K = ic[i], HCm = hc[i], OC = oc[i];
    int Mtot = 2 * HCm + OC;
    gemm_fused<<<dim3(Mtot / 64, (NV + 127) / 128), 256, 0, stream>>>(
        hin[i], Wcat[i], in(12 + 11 * i), in(14 + 11 * i), in(21 + 11 * i),
        B1, B2, B3, NV, K, HCm, 2 * HCm, Mtot);
    const int* offs = countsA + i * (NV + 1);
    const uint2* csr2 = csr2A + (size_t)i * CSRN;
    const float* easum = easumA + i * 16;
    if (i < 2) {
      fused_agg_kernel<4><<<NV, 256, 0, stream>>>(
          ea[i], easum, in(15 + 11 * i), B1, B2, in(16 + 11 * i),
          in(17 + 11 * i), in(18 + 11 * i), in(19 + 11 * i), B3,
          offs, csr2, nullptr, hout_bf[i], NE);
    } else {
      fused_agg_kernel<1><<<(NV + 3) / 4, 256, 0, stream>>>(
          ea[i], easum, in(15 + 11 * i), B1, B2, in(16 + 11 * i),
          in(17 + 11 * i), in(18 + 11 * i), in(19 + 11 * i), B3,
          offs, csr2, (float*)d_out, nullptr, NE);
    }
  }
}

// Round 8
// 660.628 us; speedup vs baseline: 2.2905x; 1.1049x over previous
//
#include <hip/hip_runtime.h>
#include <hip/hip_bf16.h>
#include <math.h>

#define NV 20000
#define NE 320000
#define CSR_PAD 8

typedef __attribute__((ext_vector_type(8))) short bf16x8;
typedef __attribute__((ext_vector_type(4))) float f32x4;

static __device__ __forceinline__ ushort f2b(float f) {
  __hip_bfloat16 h = __float2bfloat16(f);
  return *reinterpret_cast<ushort*>(&h);
}
static __device__ __forceinline__ float b2f(ushort u) {
  union { ushort s[2]; float f; } c;
  c.s[0] = 0; c.s[1] = u;
  return c.f;
}

// DPP wave-64 sum: 6 VALU adds; lane 63 holds total, broadcast via readlane.
static __device__ __forceinline__ float wave_sum64(float x) {
  x += __int_as_float(__builtin_amdgcn_update_dpp(0, __float_as_int(x), 0x111, 0xF, 0xF, true));
  x += __int_as_float(__builtin_amdgcn_update_dpp(0, __float_as_int(x), 0x112, 0xF, 0xF, true));
  x += __int_as_float(__builtin_amdgcn_update_dpp(0, __float_as_int(x), 0x114, 0xF, 0xF, true));
  x += __int_as_float(__builtin_amdgcn_update_dpp(0, __float_as_int(x), 0x118, 0xF, 0xF, true));
  x += __int_as_float(__builtin_amdgcn_update_dpp(0, __float_as_int(x), 0x142, 0xA, 0xF, true));
  x += __int_as_float(__builtin_amdgcn_update_dpp(0, __float_as_int(x), 0x143, 0xC, 0xF, true));
  return __int_as_float(__builtin_amdgcn_readlane(__float_as_int(x), 63));
}

static __device__ __forceinline__ float dot16(const float4* __restrict__ p,
                                              const float* __restrict__ Wc) {
  float4 a0 = p[0], a1 = p[1], a2 = p[2], a3 = p[3];
  float s = a0.x * Wc[0];
  s = fmaf(a0.y, Wc[1], s);  s = fmaf(a0.z, Wc[2], s);  s = fmaf(a0.w, Wc[3], s);
  s = fmaf(a1.x, Wc[4], s);  s = fmaf(a1.y, Wc[5], s);  s = fmaf(a1.z, Wc[6], s);
  s = fmaf(a1.w, Wc[7], s);  s = fmaf(a2.x, Wc[8], s);  s = fmaf(a2.y, Wc[9], s);
  s = fmaf(a2.z, Wc[10], s); s = fmaf(a2.w, Wc[11], s); s = fmaf(a3.x, Wc[12], s);
  s = fmaf(a3.y, Wc[13], s); s = fmaf(a3.z, Wc[14], s); s = fmaf(a3.w, Wc[15], s);
  return s;
}

// ---------------- batched prep: CSR hist + ea colsum (y<3), W casts (y==3), proj (y==4) ----------------
struct CJob { const float* src; ushort* dst; int K, M; };
struct PrepArgs {
  const int* ei[3];
  const float* ea[3];
  int* counts[3];
  float* easum[3];
  CJob jobs[9];
  const float *x, *Wp, *bp, *gp, *bep;
  ushort* h0;
};

__global__ __launch_bounds__(256) void prep_kernel(PrepArgs a) {
  const int y = blockIdx.y, t = threadIdx.x;
  if (y < 3) {
    // ea column sums: 256 blocks, float4 loads, one shared reduce -> 16 atomics/block
    if (blockIdx.x < 256) {
      const float4* ea4 = (const float4*)a.ea[y];
      const int cg = t & 3;
      int r = blockIdx.x * 64 + (t >> 2);
      const int rstride = 256 * 64;
      float4 s = make_float4(0.f, 0.f, 0.f, 0.f);
      for (; r < NE; r += rstride) {
        float4 v = ea4[(size_t)r * 4 + cg];
        s.x += v.x; s.y += v.y; s.z += v.z; s.w += v.w;
      }
      __shared__ float4 red4[256];
      red4[t] = s;
      __syncthreads();
      if (t < 4) {
        float4 tot = make_float4(0.f, 0.f, 0.f, 0.f);
        for (int j = t; j < 256; j += 4) {
          float4 v = red4[j];
          tot.x += v.x; tot.y += v.y; tot.z += v.z; tot.w += v.w;
        }
        atomicAdd(&a.easum[y][t * 4 + 0], tot.x);
        atomicAdd(&a.easum[y][t * 4 + 1], tot.y);
        atomicAdd(&a.easum[y][t * 4 + 2], tot.z);
        atomicAdd(&a.easum[y][t * 4 + 3], tot.w);
      }
    }
    // dst histogram over real edges only (self loops handled analytically in agg)
    int i = blockIdx.x * 256 + t;
    if (i < NE) atomicAdd(&a.counts[y][a.ei[y][NE + i]], 1);
  } else if (y == 3) {
    // weight transpose-casts
#pragma unroll
    for (int j = 0; j < 9; ++j) {
      CJob jb = a.jobs[j];
      const int total = jb.M * jb.K;
      for (int i = blockIdx.x * 256 + t; i < total; i += gridDim.x * 256) {
        int m = i / jb.K, k = i - m * jb.K;
        jb.dst[i] = f2b(jb.src[(size_t)k * jb.M + m]);
      }
    }
  } else {
    // proj: h0 = gelu(LN(x@Wp + bp)) (grid-stride over rows)
    int wid = t >> 6, lane = t & 63;
    for (int row = blockIdx.x * 4 + wid; row < NV; row += gridDim.x * 4) {
      float xv = a.x[(size_t)row * 64 + lane];
      float acc = a.bp[lane];
#pragma unroll
      for (int k = 0; k < 64; ++k) {
        float v = __shfl(xv, k, 64);
        acc = fmaf(v, a.Wp[k * 64 + lane], acc);
      }
      float s1 = wave_sum64(acc), s2 = wave_sum64(acc * acc);
      float mean = s1 * (1.0f / 64.0f);
      float var  = s2 * (1.0f / 64.0f) - mean * mean;
      float yv = (acc - mean) * rsqrtf(var + 1e-5f) * a.gp[lane] + a.bep[lane];
      float gel = 0.5f * yv * (1.0f + erff(yv * 0.70710678118654752f));
      a.h0[(size_t)row * 64 + lane] = f2b(gel);
    }
  }
}

// ---------------- batched scan: blockIdx.x = layer ----------------
__global__ __launch_bounds__(1024) void scan_kernel(
    int* __restrict__ countsA, int* __restrict__ cursorA)
{
  int* counts = countsA + blockIdx.x * (NV + 1);
  int* cursor = cursorA + blockIdx.x * NV;
  __shared__ int ws[16];
  __shared__ int wexcl[17];
  const int t = threadIdx.x, lane = t & 63, wid = t >> 6;
  const int base = t * 20;
  int v[20];
  int tot = 0;
#pragma unroll
  for (int j = 0; j < 20; ++j) {
    int i = base + j;
    v[j] = (i < NV) ? counts[i] : 0;
    tot += v[j];
  }
  int x = tot;
#pragma unroll
  for (int o = 1; o < 64; o <<= 1) {
    int yy = __shfl_up(x, o, 64);
    if (lane >= o) x += yy;
  }
  if (lane == 63) ws[wid] = x;
  __syncthreads();
  if (t == 0) {
    int r = 0;
#pragma unroll
    for (int j = 0; j < 16; ++j) { wexcl[j] = r; r += ws[j]; }
    wexcl[16] = r;
  }
  __syncthreads();
  int run = wexcl[wid] + (x - tot);
#pragma unroll
  for (int j = 0; j < 20; ++j) {
    int i = base + j;
    if (i < NV) { counts[i] = run; cursor[i] = run; }
    run += v[j];
  }
  if (t == 0) counts[NV] = wexcl[16];
}

// ---------------- batched scatter: premultiplied (src*HC, e*16) pairs ----------------
struct ScatArgs { const int* ei[3]; int* cursor[3]; uint2* csr2[3]; int HC[3]; };
__global__ __launch_bounds__(256) void scatter_kernel(ScatArgs a) {
  const int l = blockIdx.y;
  int i = blockIdx.x * 256 + threadIdx.x;
  if (i >= NE + CSR_PAD) return;
  if (i >= NE) { a.csr2[l][i] = make_uint2(0u, 0u); return; }  // prefetch pad
  int dst = a.ei[l][NE + i], src = a.ei[l][i];
  int pos = atomicAdd(&a.cursor[l][dst], 1);
  a.csr2[l][pos] = make_uint2((unsigned)(src * a.HC[l]), (unsigned)(i * 16));
}

// ---------------- fused per-layer GEMM: [xl | xr | res] = A @ [Wl|Wr|Wsk] + bias ----------------
__global__ __launch_bounds__(256) void gemm_fused(
    const ushort* __restrict__ A, const ushort* __restrict__ WT,
    const float* __restrict__ b0, const float* __restrict__ b1,
    const float* __restrict__ b2,
    ushort* __restrict__ O0, ushort* __restrict__ O1, float* __restrict__ O2,
    int N, int K, int M1, int M2, int Mtot)
{
  __shared__ ushort As[128][40];
  __shared__ ushort Bs[64][40];
  const int t = threadIdx.x, wave = t >> 6, lane = t & 63;
  const int row0 = blockIdx.y * 128, col0 = blockIdx.x * 64;
  const int m_ = lane & 15, q = lane >> 4;
  f32x4 acc[2][4];
#pragma unroll
  for (int i = 0; i < 2; ++i)
#pragma unroll
    for (int j = 0; j < 4; ++j) acc[i][j] = (f32x4){0.f, 0.f, 0.f, 0.f};

  const int ar = t >> 1, ac = (t & 1) * 16;
  const int br = t >> 2, bcol = (t & 3) * 8;
  const ushort* Ap = A + (size_t)(row0 + ar) * K + ac;
  const ushort* Bp = WT + (size_t)(col0 + br) * K + bcol;
  const bool a_ok = (row0 + ar) < N;

  for (int k0 = 0; k0 < K; k0 += 32) {
    uint4 av0 = make_uint4(0, 0, 0, 0), av1 = make_uint4(0, 0, 0, 0);
    if (a_ok) { av0 = *(const uint4*)(Ap + k0); av1 = *(const uint4*)(Ap + k0 + 8); }
    uint4 bv = *(const uint4*)(Bp + k0);
    *(uint4*)&As[ar][ac] = av0;
    *(uint4*)&As[ar][ac + 8] = av1;
    *(uint4*)&Bs[br][bcol] = bv;
    __syncthreads();
    bf16x8 a0 = *(const bf16x8*)&As[wave * 32 + m_][q * 8];
    bf16x8 a1 = *(const bf16x8*)&As[wave * 32 + 16 + m_][q * 8];
#pragma unroll
    for (int cf = 0; cf < 4; ++cf) {
      bf16x8 b = *(const bf16x8*)&Bs[cf * 16 + m_][q * 8];
      acc[0][cf] = __builtin_amdgcn_mfma_f32_16x16x32_bf16(a0, b, acc[0][cf], 0, 0, 0);
      acc[1][cf] = __builtin_amdgcn_mfma_f32_16x16x32_bf16(a1, b, acc[1][cf], 0, 0, 0);
    }
    __syncthreads();
  }

  const float* bias; int base, mode, Wd;
  if (col0 < M1)      { bias = b0; base = 0;  mode = 0; Wd = M1; }
  else if (col0 < M2) { bias = b1; base = M1; mode = 1; Wd = M2 - M1; }
  else                { bias = b2; base = M2; mode = 2; Wd = Mtot - M2; }

#pragma unroll
  for (int rf = 0; rf < 2; ++rf) {
#pragma unroll
    for (int cf = 0; cf < 4; ++cf) {
      int col = col0 + cf * 16 + m_ - base;
      float bb = bias[col];
#pragma unroll
      for (int r = 0; r < 4; ++r) {
        int row = row0 + wave * 32 + rf * 16 + q * 4 + r;
        if (row < N) {
          float v = acc[rf][cf][r] + bb;
          if (mode == 0)      O0[(size_t)row * Wd + col] = f2b(v);
          else if (mode == 1) O1[(size_t)row * Wd + col] = f2b(v);
          else                O2[(size_t)row * Wd + col] = v;
        }
      }
    }
  }
}

// ---------------- fused GATv2: score + softmax + aggregate + LN + gelu + res ----------------
// H=4: one block (4 waves) per node. H=1: one wave per node, 4 nodes/block.
// Self-loop handled analytically (CSR = real edges only). csr2 holds premultiplied
// offsets; readfirstlane scalarizes the wave-uniform csr2/ea/xl-base addressing so
// per-edge VALU is just the math. exp2 with log2(e) folded into att (exact).
template <int H>
__global__ __launch_bounds__(256, 4) void fused_agg_kernel(
    const float* __restrict__ ea, const float* __restrict__ easum,
    const float* __restrict__ We,
    const ushort* __restrict__ xl, const ushort* __restrict__ xr,
    const float* __restrict__ att, const float* __restrict__ bc,
    const float* __restrict__ g, const float* __restrict__ be,
    const float* __restrict__ res,
    const int* __restrict__ offs, const uint2* __restrict__ csr2,
    float* __restrict__ houtf, ushort* __restrict__ houtb, int E)
{
  const int HC = H * 64;
  const int t = threadIdx.x, lane = t & 63, wave = t >> 6;
  const int n = (H == 1) ? blockIdx.x * 4 + wave : blockIdx.x;
  const int c = (H == 1) ? lane : t;

  const float xr_t = b2f(xr[(size_t)n * HC + c]);
  const float att_t = att[c] * 1.4426950408889634f;  // fold log2(e): exp(s)=2^(s*log2e)
  float Wc[16];
#pragma unroll
  for (int k = 0; k < 16; ++k) Wc[k] = We[k * HC + c];
  float eself = 0.f;
#pragma unroll
  for (int k = 0; k < 16; ++k) eself = fmaf(easum[k], Wc[k], eself);
  eself *= 1.0f / (float)E;

  // self-loop contribution (analytic)
  const float xln = b2f(xl[(size_t)n * HC + c]);
  float vs = xln + xr_t + eself;
  vs = vs > 0.f ? vs : 0.2f * vs;
  const float wself = exp2f(wave_sum64(vs * att_t));
  float acc = wself * xln, denom = wself;

  const int beg = offs[n], end = offs[n + 1];

  uint2 P[4];
#pragma unroll
  for (int k = 0; k < 4; ++k) P[k] = csr2[beg + k];

  for (int idx = beg; idx < end; idx += 4) {
    uint2 Q[4];
#pragma unroll
    for (int k = 0; k < 4; ++k) Q[k] = csr2[idx + 4 + k];

    float xls[4], ee[4], wv[4];
#pragma unroll
    for (int k = 0; k < 4; ++k) {
      const unsigned so = __builtin_amdgcn_readfirstlane(P[k].x);  // src*HC (scalar)
      const unsigned eo = __builtin_amdgcn_readfirstlane(P[k].y);  // e*16 (scalar)
      const float4* p = (const float4*)(ea + eo);  // fully scalar address
      ee[k] = dot16(p, Wc);
      xls[k] = b2f(xl[so + c]);                    // sgpr base + vgpr offset
    }
#pragma unroll
    for (int k = 0; k < 4; ++k) {
      float v = xls[k] + xr_t + ee[k];
      v = v > 0.f ? v : 0.2f * v;  // leaky_relu(0.2)
      float S = wave_sum64(v * att_t);
      wv[k] = (idx + k < end) ? exp2f(S) : 0.f;
    }
#pragma unroll
    for (int k = 0; k < 4; ++k) { acc = fmaf(wv[k], xls[k], acc); denom += wv[k]; }
#pragma unroll
    for (int k = 0; k < 4; ++k) P[k] = Q[k];
  }

  float out = acc / (denom + 1e-16f) + bc[c];

  // LayerNorm across HC channels
  float s1 = wave_sum64(out), s2 = wave_sum64(out * out);
  if (H > 1) {
    __shared__ float r1s[4], r2s[4];
    if (lane == 0) { r1s[wave] = s1; r2s[wave] = s2; }
    __syncthreads();
    s1 = 0.f; s2 = 0.f;
#pragma unroll
    for (int j = 0; j < H; ++j) { s1 += r1s[j]; s2 += r2s[j]; }
  }
  float mean = s1 / (float)HC;
  float var  = s2 / (float)HC - mean * mean;
  float y = (out - mean) * rsqrtf(var + 1e-5f) * g[c] + be[c];
  float gel = 0.5f * y * (1.0f + erff(y * 0.70710678118654752f));
  float o = gel + res[(size_t)n * HC + c];
  if (houtf) houtf[(size_t)n * HC + c] = o;
  if (houtb) houtb[(size_t)n * HC + c] = f2b(o);
}

// ---------------- host launch ----------------
extern "C" void kernel_launch(void* const* d_in, const int* in_sizes, int n_in,
                              void* d_out, int out_size, void* d_ws, size_t ws_size,
                              hipStream_t stream)
{
  const float* x = (const float*)d_in[0];
  const int*   ei[3] = {(const int*)d_in[1], (const int*)d_in[3], (const int*)d_in[5]};
  const float* ea[3] = {(const float*)d_in[2], (const float*)d_in[4], (const float*)d_in[6]};
  auto in = [&](int i) { return (const float*)d_in[i]; };
  // per-layer base 11 + 11*i: Wl, bl, Wr, br, We, att, bc, g, be, Wsk, bsk

  const int ic[3] = {64, 256, 256}, hc[3] = {256, 256, 64}, oc[3] = {256, 256, 64};
  const int CSRN = NE + CSR_PAD;

  // ---- workspace layout (~74 MB) ----
  char* w = (char*)d_ws;
  size_t off = 0;
  auto alloc = [&](size_t bytes) { void* p = w + off; off = (off + bytes + 511) & ~(size_t)511; return p; };
  ushort* B1   = (ushort*)alloc((size_t)NV * 256 * 2);  // xl (bf16)
  ushort* B2   = (ushort*)alloc((size_t)NV * 256 * 2);  // xr (bf16)
  float*  B3   = (float*)alloc((size_t)NV * 256 * 4);   // res (f32)
  ushort* h0bf = (ushort*)alloc((size_t)NV * 64 * 2);
  ushort* h1bf = (ushort*)alloc((size_t)NV * 256 * 2);
  ushort* h2bf = (ushort*)alloc((size_t)NV * 256 * 2);
  ushort* Wcat[3];
  for (int i = 0; i < 3; ++i)
    Wcat[i] = (ushort*)alloc((size_t)(2 * hc[i] + oc[i]) * ic[i] * 2);
  float* easumA  = (float*)alloc(3 * 64);                    // 3 x 16 floats
  int*   countsA = (int*)alloc((size_t)3 * (NV + 1) * 4);    // adjacent to easumA for one memset
  int*   cursorA = (int*)alloc((size_t)3 * NV * 4);
  uint2* csr2A   = (uint2*)alloc((size_t)3 * CSRN * 8);

  // ---- single memset: easums + counts ----
  hipMemsetAsync(easumA, 0, 512 + (size_t)3 * (NV + 1) * 4, stream);

  // ---- batched prep: CSR hist + colsum (x3), weight casts, proj ----
  PrepArgs pa;
  for (int i = 0; i < 3; ++i) {
    pa.ei[i] = ei[i];
    pa.ea[i] = ea[i];
    pa.counts[i] = countsA + i * (NV + 1);
    pa.easum[i] = easumA + i * 16;
    pa.jobs[i * 3 + 0] = {in(11 + 11 * i), Wcat[i],                             ic[i], hc[i]};
    pa.jobs[i * 3 + 1] = {in(13 + 11 * i), Wcat[i] + (size_t)hc[i] * ic[i],     ic[i], hc[i]};
    pa.jobs[i * 3 + 2] = {in(20 + 11 * i), Wcat[i] + (size_t)2 * hc[i] * ic[i], ic[i], oc[i]};
  }
  pa.x = x; pa.Wp = in(7); pa.bp = in(8); pa.gp = in(9); pa.bep = in(10); pa.h0 = h0bf;
  prep_kernel<<<dim3(1344, 5), 256, 0, stream>>>(pa);

  // ---- batched scan + scatter ----
  scan_kernel<<<3, 1024, 0, stream>>>(countsA, cursorA);
  ScatArgs sa;
  for (int i = 0; i < 3; ++i) {
    sa.ei[i] = ei[i];
    sa.cursor[i] = cursorA + i * NV;
    sa.csr2[i] = csr2A + (size_t)i * CSRN;
    sa.HC[i] = hc[i];
  }
  scatter_kernel<<<dim3((NE + CSR_PAD + 255) / 256, 3), 256, 0, stream>>>(sa);

  // ---- per-layer: fused GEMM + fused aggregate ----
  const ushort* hin[3] = {h0bf, h1bf, h2bf};
  ushort* hout_bf[3] = {h1bf, h2bf, nullptr};
  for (int i = 0; i < 3; ++i) {
    int K = ic[i], HCm = hc[i], OC = oc[i];
    int Mtot = 2 * HCm + OC;
    gemm_fused<<<dim3(Mtot / 64, (NV + 127) / 128), 256, 0, stream>>>(
        hin[i], Wcat[i], in(12 + 11 * i), in(14 + 11 * i), in(21 + 11 * i),
        B1, B2, B3, NV, K, HCm, 2 * HCm, Mtot);
    const int* offs = countsA + i * (NV + 1);
    const uint2* csr2 = csr2A + (size_t)i * CSRN;
    const float* easum = easumA + i * 16;
    if (i < 2) {
      fused_agg_kernel<4><<<NV, 256, 0, stream>>>(
          ea[i], easum, in(15 + 11 * i), B1, B2, in(16 + 11 * i),
          in(17 + 11 * i), in(18 + 11 * i), in(19 + 11 * i), B3,
          offs, csr2, nullptr, hout_bf[i], NE);
    } else {
      fused_agg_kernel<1><<<(NV + 3) / 4, 256, 0, stream>>>(
          ea[i], easum, in(15 + 11 * i), B1, B2, in(16 + 11 * i),
          in(17 + 11 * i), in(18 + 11 * i), in(19 + 11 * i), B3,
          offs, csr2, (float*)d_out, nullptr, NE);
    }
  }
}